// Round 13
// baseline (541.407 us; speedup 1.0000x reference)
//
#include <hip/hip_runtime.h>

typedef float f4 __attribute__((ext_vector_type(4)));
typedef float f32x4 __attribute__((ext_vector_type(4)));
typedef unsigned short us8 __attribute__((ext_vector_type(8)));
typedef __bf16 bf8 __attribute__((ext_vector_type(8)));

static constexpr int B_ = 2, S_ = 1024, H_ = 2048, T_ = B_ * S_;
static constexpr int NH_ = 16, DN_ = 128, DR_ = 64, DV_ = 128, DQK_ = 192;
static constexpr int KVL_ = 512, QL_ = 1536, INTER_ = 768, NEXP_ = 8, NE9_ = 9;
static constexpr int QKA_ = 2176;  // 1536 (q_a) + 576 (kv_a) + 64 pad
static constexpr float SCALING_ = 0.07216878364870322f; // 192^-0.5
static constexpr float EPS_ = 1e-6f;

__device__ __forceinline__ unsigned short f2bf(float f) {
    unsigned u = __float_as_uint(f);
    u += 0x7fffu + ((u >> 16) & 1u);
    return (unsigned short)(u >> 16);
}
__device__ __forceinline__ float bf2f(unsigned short h) {
    return __uint_as_float(((unsigned)h) << 16);
}
__device__ __forceinline__ us8 pack8(f4 a, f4 b) {
    us8 r;
    r[0] = f2bf(a[0]); r[1] = f2bf(a[1]); r[2] = f2bf(a[2]); r[3] = f2bf(a[3]);
    r[4] = f2bf(b[0]); r[5] = f2bf(b[1]); r[6] = f2bf(b[2]); r[7] = f2bf(b[3]);
    return r;
}

// async 16B/lane global->LDS. LDS dest = wave-uniform base + lane*16 (HW).
__device__ __forceinline__ void gload16(const unsigned short* g, unsigned short* lds) {
    __builtin_amdgcn_global_load_lds(
        (const __attribute__((address_space(1))) void*)g,
        (__attribute__((address_space(3))) void*)lds, 16, 0, 0);
}

// ---------------------------------------------------------------------------
// gemm2: C[M,N] = A[M,K] * B[N,K]^T, A bf16; B bf16 (BF32=0, global_load_lds)
// or fp32 (BF32=1, T14 reg-stage: issue dwordx4 early -> pack8 -> ds_write
// into the SAME swizzled LDS slot). 128x128 tile, BK=64, 2-buffer counted
// pipeline, chunk-XOR swizzle (r9-verified, 0 conflicts), T1 XCD swizzle, T5.
// MODE 0: plain. Cb -> bf16; else Cf (+add, may alias Cf) fp32.
// MODE 2: A rows compacted at off[e] (z=expert), C bf16 compacted rows;
//         BF32 B source = Bv + z*sB for z<8, Bv2 for z==8.
// ---------------------------------------------------------------------------
template <int MODE, int BF32>
__global__ __launch_bounds__(256) void gemm2(
    const unsigned short* __restrict__ A, const void* __restrict__ Bv,
    const void* __restrict__ Bv2,
    float* __restrict__ Cf, unsigned short* __restrict__ Cb,
    const float* __restrict__ add,
    const int* __restrict__ cnt, const int* __restrict__ off,
    int M, int N, int K, int ldA, long sB)
{
    constexpr int BM = 128, BN = 128, BK = 64;
    __shared__ __align__(16) unsigned short As[2][BM * BK];
    __shared__ __align__(16) unsigned short Bs[2][BN * BK];
    const int tid = threadIdx.x, lane = tid & 63, wv = tid >> 6;
    const int wm = (wv >> 1) * 64, wn = (wv & 1) * 64;

    const int nb = gridDim.x * gridDim.y;
    const int lin = blockIdx.y * gridDim.x + blockIdx.x;
    const int swz = (lin & 7) * (nb >> 3) + (lin >> 3);
    const int bx = swz % gridDim.x;
    const int by = swz / gridDim.x;
    const int m0 = bx * BM, n0 = by * BN;

    int mcnt = M, obase = 0;
    if constexpr (MODE == 2) {
        mcnt = cnt[blockIdx.z];
        if (m0 >= mcnt) return;
        obase = off[blockIdx.z];
    }

    const unsigned short* Bb = (const unsigned short*)Bv;
    const float* Bf = nullptr;
    if constexpr (BF32) {
        if constexpr (MODE == 2)
            Bf = (blockIdx.z < 8) ? ((const float*)Bv + (long)blockIdx.z * sB)
                                  : (const float*)Bv2;
        else
            Bf = (const float*)Bv;
    }

    const int srow = tid >> 3;                       // 0..31 within site
    const int scol = (((tid & 7) ^ (srow & 7)) * 8); // pre-swizzled global col
    long aoff[4], boff[4];
#pragma unroll
    for (int s = 0; s < 4; s++) {
        int r = m0 + s * 32 + srow;
        if constexpr (MODE == 2) {
            aoff[s] = (long)(obase + r) * ldA + scol;
        } else {
            aoff[s] = (long)r * ldA + scol;
        }
        if constexpr (BF32)
            boff[s] = (long)(n0 + s * 32 + srow) * K + scol;
        else
            boff[s] = (long)blockIdx.z * sB + (long)(n0 + s * 32 + srow) * K + scol;
    }

    f32x4 acc[4][4];
#pragma unroll
    for (int m = 0; m < 4; m++)
#pragma unroll
        for (int n = 0; n < 4; n++) acc[m][n] = f32x4{0.f, 0.f, 0.f, 0.f};

    const int fr = lane & 15, lg = lane >> 4;
    const int xr = fr & 7;

    auto stageA = [&](int buf, int k0) {
#pragma unroll
        for (int s = 0; s < 4; s++)
            gload16(A + aoff[s] + k0, &As[buf][s * 2048 + wv * 512]);
    };
    f4 brg[4][2];
    auto issueB = [&](int k0) {
#pragma unroll
        for (int s = 0; s < 4; s++) {
            brg[s][0] = *(const f4*)(Bf + boff[s] + k0);
            brg[s][1] = *(const f4*)(Bf + boff[s] + k0 + 4);
        }
    };
    auto writeB = [&](int buf) {
#pragma unroll
        for (int s = 0; s < 4; s++)
            *(us8*)&Bs[buf][s * 2048 + srow * 64 + (tid & 7) * 8] = pack8(brg[s][0], brg[s][1]);
    };
    auto compute = [&](int buf) {
        __builtin_amdgcn_s_setprio(1);
        bf8 af[4][2], bfv[4][2];
#pragma unroll
        for (int m = 0; m < 4; m++) {
            int R = wm + m * 16 + fr;
#pragma unroll
            for (int ks = 0; ks < 2; ks++)
                af[m][ks] = *(const bf8*)&As[buf][R * 64 + ((ks * 4 + lg) ^ xr) * 8];
        }
#pragma unroll
        for (int n = 0; n < 4; n++) {
            int R = wn + n * 16 + fr;
#pragma unroll
            for (int ks = 0; ks < 2; ks++)
                bfv[n][ks] = *(const bf8*)&Bs[buf][R * 64 + ((ks * 4 + lg) ^ xr) * 8];
        }
#pragma unroll
        for (int m = 0; m < 4; m++)
#pragma unroll
            for (int n = 0; n < 4; n++) {
                acc[m][n] = __builtin_amdgcn_mfma_f32_16x16x32_bf16(af[m][0], bfv[n][0], acc[m][n], 0, 0, 0);
                acc[m][n] = __builtin_amdgcn_mfma_f32_16x16x32_bf16(af[m][1], bfv[n][1], acc[m][n], 0, 0, 0);
            }
        __builtin_amdgcn_s_setprio(0);
    };

    const int nt = K / BK;
    if constexpr (BF32 == 0) {
        // original verified path: B via global_load_lds
        auto stageB = [&](int buf, int k0) {
#pragma unroll
            for (int s = 0; s < 4; s++)
                gload16(Bb + boff[s] + k0, &Bs[buf][s * 2048 + wv * 512]);
        };
        stageA(0, 0);
        stageB(0, 0);
        for (int t = 0; t < nt; t++) {
            if (t + 1 < nt) {
                stageA((t & 1) ^ 1, (t + 1) * BK);
                stageB((t & 1) ^ 1, (t + 1) * BK);
                asm volatile("s_waitcnt vmcnt(8)" ::: "memory");
            } else {
                asm volatile("s_waitcnt vmcnt(0)" ::: "memory");
            }
            __builtin_amdgcn_s_barrier();
            compute(t & 1);
            __builtin_amdgcn_s_barrier();
        }
    } else {
        // fp32-B reg-staged path. Issue order: B regs first, then A lds.
        issueB(0);
        stageA(0, 0);
        writeB(0);                                   // compiler waits brg
        asm volatile("s_waitcnt lgkmcnt(0)" ::: "memory");
        for (int t = 0; t < nt; t++) {
            if (t + 1 < nt) {
                issueB((t + 1) * BK);
                stageA((t & 1) ^ 1, (t + 1) * BK);
                asm volatile("s_waitcnt vmcnt(12)" ::: "memory");  // A(t) landed
            } else {
                asm volatile("s_waitcnt vmcnt(0)" ::: "memory");
            }
            __builtin_amdgcn_s_barrier();
            compute(t & 1);
            if (t + 1 < nt) writeB((t & 1) ^ 1);     // compiler waits brg
            asm volatile("s_waitcnt lgkmcnt(0)" ::: "memory");
            __builtin_amdgcn_s_barrier();
        }
    }

#pragma unroll
    for (int m = 0; m < 4; m++) {
#pragma unroll
        for (int n = 0; n < 4; n++) {
#pragma unroll
            for (int i = 0; i < 4; i++) {
                int row = wm + m * 16 + lg * 4 + i;
                int col = n0 + wn + n * 16 + fr;
                float v = acc[m][n][i];
                if constexpr (MODE == 0) {
                    long idx = (long)(m0 + row) * N + col;
                    if (Cb)       Cb[idx] = f2bf(v);
                    else if (add) Cf[idx] = v + add[idx];
                    else          Cf[idx] = v;
                } else {
                    if (m0 + row < mcnt)
                        Cb[(long)(obase + m0 + row) * N + col] = f2bf(v);
                }
            }
        }
    }
}

// ---------------------------------------------------------------------------
// gemm_gu: fused MoE gate+up+silu, BM=64, BN=64 (+64 up), fp32 weights read
// DIRECTLY (gw/uw, shared sgw/suw at z==8) via reg-stage. LDS 48 KB ->
// 3 blocks/CU. Epilogue: actm = bf16(silu(g)*u) compacted at off[z].
// ---------------------------------------------------------------------------
__global__ __launch_bounds__(256) void gemm_gu(
    const unsigned short* __restrict__ A,
    const float* __restrict__ gw, const float* __restrict__ uw,
    const float* __restrict__ sgw, const float* __restrict__ suw,
    unsigned short* __restrict__ actm,
    const int* __restrict__ cnt, const int* __restrict__ off,
    const int* __restrict__ idxl)
{
    constexpr int BM = 64, BN = 64, BK = 64, K = H_;
    __shared__ __align__(16) unsigned short As[2][BM * BK];   // 8 KB x2
    __shared__ __align__(16) unsigned short Bg[2][BN * BK];   // 8 KB x2
    __shared__ __align__(16) unsigned short Bu[2][BN * BK];   // 8 KB x2
    const int tid = threadIdx.x, lane = tid & 63, wv = tid >> 6;
    const int wm = (wv >> 1) * 32, wn = (wv & 1) * 32;

    const int nb = gridDim.x * gridDim.y;     // 32*12=384, %8==0
    const int lin = blockIdx.y * gridDim.x + blockIdx.x;
    const int swz = (lin & 7) * (nb >> 3) + (lin >> 3);
    const int bx = swz % gridDim.x;
    const int by = swz / gridDim.x;
    const int m0 = bx * BM, n0 = by * BN;
    const int e = blockIdx.z;

    const int mcnt = cnt[e];
    if (m0 >= mcnt) return;
    const int obase = off[e];

    const float* gW = (e < 8) ? (gw + (long)e * INTER_ * H_) : sgw;
    const float* uW = (e < 8) ? (uw + (long)e * INTER_ * H_) : suw;

    const int srow = tid >> 3;
    const int scol = (((tid & 7) ^ (srow & 7)) * 8);
    long aoff[2], bro[2];
#pragma unroll
    for (int s = 0; s < 2; s++) {
        int r = m0 + s * 32 + srow;
        int rc = (r < mcnt) ? r : mcnt - 1;
        aoff[s] = (long)idxl[(long)e * T_ + rc] * H_ + scol;
        bro[s] = (long)(n0 + s * 32 + srow) * K + scol;
    }

    f32x4 ag[2][2], au[2][2];
#pragma unroll
    for (int m = 0; m < 2; m++)
#pragma unroll
        for (int n = 0; n < 2; n++) {
            ag[m][n] = f32x4{0.f, 0.f, 0.f, 0.f};
            au[m][n] = f32x4{0.f, 0.f, 0.f, 0.f};
        }

    const int fr = lane & 15, lg = lane >> 4;
    const int xr = fr & 7;

    auto stageA = [&](int buf, int k0) {
#pragma unroll
        for (int s = 0; s < 2; s++)
            gload16(A + aoff[s] + k0, &As[buf][s * 2048 + wv * 512]);
    };
    f4 brg[4][2];   // sites 0-1: gate, 2-3: up
    auto issueB = [&](int k0) {
#pragma unroll
        for (int s = 0; s < 2; s++) {
            brg[s][0] = *(const f4*)(gW + bro[s] + k0);
            brg[s][1] = *(const f4*)(gW + bro[s] + k0 + 4);
            brg[2 + s][0] = *(const f4*)(uW + bro[s] + k0);
            brg[2 + s][1] = *(const f4*)(uW + bro[s] + k0 + 4);
        }
    };
    auto writeB = [&](int buf) {
#pragma unroll
        for (int s = 0; s < 2; s++) {
            *(us8*)&Bg[buf][s * 2048 + (srow & 31) * 64 + (tid & 7) * 8] = pack8(brg[s][0], brg[s][1]);
            *(us8*)&Bu[buf][s * 2048 + (srow & 31) * 64 + (tid & 7) * 8] = pack8(brg[2 + s][0], brg[2 + s][1]);
        }
    };
    auto compute = [&](int buf) {
        __builtin_amdgcn_s_setprio(1);
        bf8 af[2][2], bgf[2][2], buf_[2][2];
#pragma unroll
        for (int m = 0; m < 2; m++) {
            int R = wm + m * 16 + fr;
#pragma unroll
            for (int ks = 0; ks < 2; ks++)
                af[m][ks] = *(const bf8*)&As[buf][R * 64 + ((ks * 4 + lg) ^ xr) * 8];
        }
#pragma unroll
        for (int n = 0; n < 2; n++) {
            int R = wn + n * 16 + fr;
#pragma unroll
            for (int ks = 0; ks < 2; ks++) {
                bgf[n][ks] = *(const bf8*)&Bg[buf][R * 64 + ((ks * 4 + lg) ^ xr) * 8];
                buf_[n][ks] = *(const bf8*)&Bu[buf][R * 64 + ((ks * 4 + lg) ^ xr) * 8];
            }
        }
#pragma unroll
        for (int m = 0; m < 2; m++)
#pragma unroll
            for (int n = 0; n < 2; n++) {
                ag[m][n] = __builtin_amdgcn_mfma_f32_16x16x32_bf16(af[m][0], bgf[n][0], ag[m][n], 0, 0, 0);
                ag[m][n] = __builtin_amdgcn_mfma_f32_16x16x32_bf16(af[m][1], bgf[n][1], ag[m][n], 0, 0, 0);
                au[m][n] = __builtin_amdgcn_mfma_f32_16x16x32_bf16(af[m][0], buf_[n][0], au[m][n], 0, 0, 0);
                au[m][n] = __builtin_amdgcn_mfma_f32_16x16x32_bf16(af[m][1], buf_[n][1], au[m][n], 0, 0, 0);
            }
        __builtin_amdgcn_s_setprio(0);
    };

    const int nt = K / BK;   // 32
    issueB(0);
    stageA(0, 0);
    writeB(0);
    asm volatile("s_waitcnt lgkmcnt(0)" ::: "memory");
    for (int t = 0; t < nt; t++) {
        if (t + 1 < nt) {
            issueB((t + 1) * BK);
            stageA((t & 1) ^ 1, (t + 1) * BK);
            asm volatile("s_waitcnt vmcnt(10)" ::: "memory");   // A(t) landed
        } else {
            asm volatile("s_waitcnt vmcnt(0)" ::: "memory");
        }
        __builtin_amdgcn_s_barrier();
        compute(t & 1);
        if (t + 1 < nt) writeB((t & 1) ^ 1);
        asm volatile("s_waitcnt lgkmcnt(0)" ::: "memory");
        __builtin_amdgcn_s_barrier();
    }

#pragma unroll
    for (int m = 0; m < 2; m++) {
#pragma unroll
        for (int n = 0; n < 2; n++) {
#pragma unroll
            for (int i = 0; i < 4; i++) {
                int row = wm + m * 16 + lg * 4 + i;
                if (m0 + row < mcnt) {
                    float g = ag[m][n][i], u = au[m][n][i];
                    float v = g / (1.f + __expf(-g)) * u;
                    actm[(long)(obase + m0 + row) * INTER_ + n0 + wn + n * 16 + fr] = f2bf(v);
                }
            }
        }
    }
}

// ---------------------------------------------------------------------------
// Flash attention (causal). grid (S/64, B*NH), 256 threads (4 waves).
// q-tile index reversed for heads y>=16 so co-resident block pairs have
// complementary causal workloads (x, 15-x) -> balanced CUs.
// ---------------------------------------------------------------------------
__global__ __launch_bounds__(256) void fa_k(
    const unsigned short* __restrict__ qs, const unsigned short* __restrict__ ks,
    const unsigned short* __restrict__ vt, unsigned short* __restrict__ ab)
{
    constexpr int KB = 64;
    const int qx = (blockIdx.y & 16) ? (gridDim.x - 1 - (int)blockIdx.x) : (int)blockIdx.x;
    const int q0 = qx * 64;
    const int bh = blockIdx.y;
    const int b = bh >> 4, h = bh & 15;
    const int tid = threadIdx.x, lane = tid & 63, wv = tid >> 6;
    const int fr = lane & 15, lg = lane >> 4;
    const int ko = lg * 8;

    __shared__ __align__(16) unsigned short Kl[KB][200];
    __shared__ __align__(16) unsigned short Vl[128][72];
    __shared__ __align__(16) unsigned short Pl[4][16][72];

    const unsigned short* qp = qs + ((long)bh * S_ + q0 + wv * 16 + fr) * DQK_ + ko;
    bf8 qf[6];
#pragma unroll
    for (int s = 0; s < 6; s++) qf[s] = *(const bf8*)(qp + s * 32);

    f32x4 o[8];
#pragma unroll
    for (int n = 0; n < 8; n++) o[n] = f32x4{0.f, 0.f, 0.f, 0.f};
    float mrow[4] = {-3e38f, -3e38f, -3e38f, -3e38f};
    float lrow[4] = {0.f, 0.f, 0.f, 0.f};

    const int nt = q0 / KB + 1;

    const unsigned short* kg = ks + ((long)bh * S_ + (tid >> 2)) * DQK_ + (tid & 3) * 48;
    const unsigned short* vg = vt + ((long)bh * DV_ + (tid >> 1)) * S_ + (tid & 1) * 32;

    us8 krg[6], vrg[4];
#pragma unroll
    for (int j = 0; j < 6; j++) krg[j] = *(const us8*)(kg + j * 8);
#pragma unroll
    for (int j = 0; j < 4; j++) vrg[j] = *(const us8*)(vg + j * 8);

    for (int t = 0; t < nt; t++) {
        __syncthreads();
        {
            int r = tid >> 2, c = (tid & 3) * 48;
#pragma unroll
            for (int j = 0; j < 6; j++) *(us8*)&Kl[r][c + j * 8] = krg[j];
            int dv = tid >> 1, c2 = (tid & 1) * 32;
#pragma unroll
            for (int j = 0; j < 4; j++) *(us8*)&Vl[dv][c2 + j * 8] = vrg[j];
        }
        __syncthreads();
        if (t + 1 < nt) {
            long kof = (long)(t + 1) * KB;
#pragma unroll
            for (int j = 0; j < 6; j++) krg[j] = *(const us8*)(kg + kof * DQK_ + j * 8);
#pragma unroll
            for (int j = 0; j < 4; j++) vrg[j] = *(const us8*)(vg + kof + j * 8);
        }
        f32x4 ps[4];
#pragma unroll
        for (int ct = 0; ct < 4; ct++) {
            f32x4 a = f32x4{0.f, 0.f, 0.f, 0.f};
#pragma unroll
            for (int s = 0; s < 6; s++) {
                bf8 kf = *(const bf8*)&Kl[ct * 16 + fr][s * 32 + ko];
                a = __builtin_amdgcn_mfma_f32_16x16x32_bf16(qf[s], kf, a, 0, 0, 0);
            }
            ps[ct] = a;
        }
        const int kv0 = t * KB;
        const bool diag = (kv0 == q0);
#pragma unroll
        for (int ct = 0; ct < 4; ct++)
#pragma unroll
            for (int i = 0; i < 4; i++) {
                float v = ps[ct][i] * SCALING_;
                if (diag && (kv0 + ct * 16 + fr) > (q0 + wv * 16 + lg * 4 + i)) v = -3e38f;
                ps[ct][i] = v;
            }
        float scl[4];
#pragma unroll
        for (int i = 0; i < 4; i++) {
            float v = fmaxf(fmaxf(ps[0][i], ps[1][i]), fmaxf(ps[2][i], ps[3][i]));
#pragma unroll
            for (int x = 8; x; x >>= 1) v = fmaxf(v, __shfl_xor(v, x, 16));
            float mn = fmaxf(mrow[i], v);
            scl[i] = __expf(mrow[i] - mn);
            mrow[i] = mn;
        }
        float tsum[4] = {0.f, 0.f, 0.f, 0.f};
#pragma unroll
        for (int ct = 0; ct < 4; ct++)
#pragma unroll
            for (int i = 0; i < 4; i++) {
                float e = __expf(ps[ct][i] - mrow[i]);
                tsum[i] += e;
                Pl[wv][lg * 4 + i][ct * 16 + fr] = f2bf(e);
            }
#pragma unroll
        for (int i = 0; i < 4; i++) {
            float v = tsum[i];
#pragma unroll
            for (int x = 8; x; x >>= 1) v += __shfl_xor(v, x, 16);
            lrow[i] = lrow[i] * scl[i] + v;
        }
#pragma unroll
        for (int n = 0; n < 8; n++)
#pragma unroll
            for (int i = 0; i < 4; i++) o[n][i] *= scl[i];
        bf8 pf[2];
#pragma unroll
        for (int ksl = 0; ksl < 2; ksl++)
            pf[ksl] = *(const bf8*)&Pl[wv][fr][ksl * 32 + ko];
#pragma unroll
        for (int n = 0; n < 8; n++)
#pragma unroll
            for (int ksl = 0; ksl < 2; ksl++) {
                bf8 vf = *(const bf8*)&Vl[n * 16 + fr][ksl * 32 + ko];
                o[n] = __builtin_amdgcn_mfma_f32_16x16x32_bf16(pf[ksl], vf, o[n], 0, 0, 0);
            }
    }
#pragma unroll
    for (int i = 0; i < 4; i++) {
        float inv = 1.f / lrow[i];
        long rbase = ((long)b * S_ + q0 + wv * 16 + lg * 4 + i) * H_ + h * DV_;
#pragma unroll
        for (int n = 0; n < 8; n++)
            ab[rbase + n * 16 + fr] = f2bf(o[n][i] * inv);
    }
}

// ---------------------------------------------------------------------------
// merged q_a|kv_a weights: rows [0,1536)=qaw, [1536,2112)=kvaw, [2112,2176)=0
__global__ __launch_bounds__(256) void cvt_qka_k(
    const float* __restrict__ qa, const float* __restrict__ kva,
    unsigned short* __restrict__ d)
{
    long i = ((long)blockIdx.x * 256 + threadIdx.x) * 8;   // over 2176*2048
    long row = i >> 11, col = i & 2047;
    us8 o;
    if (row < QL_) {
        const float* s = qa + row * H_ + col;
        o = pack8(*(const f4*)s, *(const f4*)(s + 4));
    } else if (row < QL_ + 576) {
        const float* s = kva + (row - QL_) * H_ + col;
        o = pack8(*(const f4*)s, *(const f4*)(s + 4));
    } else {
        o = us8{0, 0, 0, 0, 0, 0, 0, 0};
    }
    *(us8*)(d + i) = o;
}

// ---------------------------------------------------------------------------
// rmsnorm fp32->bf16 (+ optional fp32 copy); cols == H_ == 2048 (8/thread)
__global__ __launch_bounds__(256) void rmsnorm_f2b(
    const float* __restrict__ in, const float* __restrict__ w,
    unsigned short* __restrict__ ob, float* __restrict__ of)
{
    const long base = (long)blockIdx.x * H_;
    const int c = threadIdx.x * 8;
    f4 v0 = *(const f4*)(in + base + c);
    f4 v1 = *(const f4*)(in + base + c + 4);
    float ss = v0[0] * v0[0] + v0[1] * v0[1] + v0[2] * v0[2] + v0[3] * v0[3]
             + v1[0] * v1[0] + v1[1] * v1[1] + v1[2] * v1[2] + v1[3] * v1[3];
#pragma unroll
    for (int o = 32; o; o >>= 1) ss += __shfl_down(ss, o);
    __shared__ float red[4];
    if ((threadIdx.x & 63) == 0) red[threadIdx.x >> 6] = ss;
    __syncthreads();
    float r = rsqrtf((red[0] + red[1] + red[2] + red[3]) / H_ + EPS_);
    f4 w0 = *(const f4*)(w + c);
    f4 w1 = *(const f4*)(w + c + 4);
    f4 a, b;
#pragma unroll
    for (int j = 0; j < 4; j++) { a[j] = v0[j] * r * w0[j]; b[j] = v1[j] * r * w1[j]; }
    *(us8*)(ob + base + c) = pack8(a, b);
    if (of) {
        *(f4*)(of + base + c) = a;
        *(f4*)(of + base + c + 4) = b;
    }
}

// bf16 in (istride) -> bf16 out (ostride); in==out safe (per-thread RBW)
__global__ __launch_bounds__(256) void rmsnorm_b2b(
    const unsigned short* __restrict__ in, const float* __restrict__ w,
    unsigned short* __restrict__ out, int cols, int istride, int ostride)
{
    const long ib = (long)blockIdx.x * istride;
    const long ob = (long)blockIdx.x * ostride;
    const int nu = cols >> 3;
    float ss = 0.f;
    for (int u = threadIdx.x; u < nu; u += 256) {
        us8 v = *(const us8*)(in + ib + u * 8);
#pragma unroll
        for (int j = 0; j < 8; j++) { float f = bf2f(v[j]); ss += f * f; }
    }
#pragma unroll
    for (int o = 32; o; o >>= 1) ss += __shfl_down(ss, o);
    __shared__ float red[4];
    if ((threadIdx.x & 63) == 0) red[threadIdx.x >> 6] = ss;
    __syncthreads();
    float r = rsqrtf((red[0] + red[1] + red[2] + red[3]) / cols + EPS_);
    for (int u = threadIdx.x; u < nu; u += 256) {
        us8 v = *(const us8*)(in + ib + u * 8);
        f4 w0 = *(const f4*)(w + u * 8);
        f4 w1 = *(const f4*)(w + u * 8 + 4);
        us8 o;
#pragma unroll
        for (int j = 0; j < 4; j++) o[j] = f2bf(bf2f(v[j]) * r * w0[j]);
#pragma unroll
        for (int j = 0; j < 4; j++) o[4 + j] = f2bf(bf2f(v[4 + j]) * r * w1[j]);
        *(us8*)(out + ob + u * 8) = o;
    }
}

// ---------------------------------------------------------------------------
__global__ __launch_bounds__(64) void rope_q_k(
    const unsigned short* __restrict__ q, const float* __restrict__ cs,
    const float* __restrict__ sn, unsigned short* __restrict__ qs)
{
    int t = blockIdx.x;            // (b*S+s)*16 + h
    int h = t & 15;
    int bs = t >> 4;
    int s = bs & (S_ - 1);
    int b = bs >> 10;
    const unsigned short* qrow = q + (long)bs * (NH_ * DQK_) + h * DQK_;
    unsigned short* orow = qs + ((long)(b * NH_ + h) * S_ + s) * DQK_;
    int l = threadIdx.x;
    orow[l] = qrow[l];
    orow[l + 64] = qrow[l + 64];
    int j = l & 31;
    float x0 = bf2f(qrow[DN_ + 2 * j]), x1 = bf2f(qrow[DN_ + 2 * j + 1]);
    float c = cs[(long)bs * DR_ + j], si = sn[(long)bs * DR_ + j];
    if (l < 32) orow[DN_ + j] = f2bf(x0 * c - x1 * si);
    else        orow[DN_ + 32 + j] = f2bf(x1 * c + x0 * si);
}

// k_rot lives in qkab cols [QL_+512, QL_+576), row stride QKA_
__global__ __launch_bounds__(64) void rope_k_k(
    const unsigned short* __restrict__ qkab, const float* __restrict__ cs,
    const float* __restrict__ sn, unsigned short* __restrict__ ks)
{
    int bs = blockIdx.x;
    int s = bs & (S_ - 1);
    int b = bs >> 10;
    const unsigned short* kr = qkab + (long)bs * QKA_ + QL_ + KVL_;
    int l = threadIdx.x;
    int j = l & 31;
    float x0 = bf2f(kr[2 * j]), x1 = bf2f(kr[2 * j + 1]);
    float c = cs[(long)bs * DR_ + j], si = sn[(long)bs * DR_ + j];
    float val = (l < 32) ? (x0 * c - x1 * si) : (x1 * c + x0 * si);
    int off = (l < 32) ? (DN_ + j) : (DN_ + 32 + j);
    unsigned short bv = f2bf(val);
    for (int h = 0; h < NH_; h++)
        ks[((long)(b * NH_ + h) * S_ + s) * DQK_ + off] = bv;
}

__global__ __launch_bounds__(128) void kpass_k(
    const unsigned short* __restrict__ kv, unsigned short* __restrict__ ks)
{
    int t = blockIdx.x; // (b*S+s)*16 + h
    int h = t & 15;
    int bs = t >> 4;
    int s = bs & (S_ - 1);
    int b = bs >> 10;
    ks[((long)(b * NH_ + h) * S_ + s) * DQK_ + threadIdx.x] = kv[(long)t * 256 + threadIdx.x];
}

// V transpose: kv (B,S,NH,256)[:,128:] -> vt (B,NH,128,S), vectorized
__global__ __launch_bounds__(256) void vt_k(
    const unsigned short* __restrict__ kv, unsigned short* __restrict__ vt)
{
    __shared__ unsigned short tile[64][DV_ + 8];
    int s0 = blockIdx.x * 64;
    int bh = blockIdx.y;
    int b = bh >> 4, h = bh & 15;
#pragma unroll
    for (int it = 0; it < 4; it++) {
        int idx = it * 256 + threadIdx.x;
        int sl = idx >> 4, du = idx & 15;
        *(us8*)&tile[sl][du * 8] =
            *(const us8*)(kv + ((long)(b * S_ + s0 + sl) * NH_ + h) * 256 + DN_ + du * 8);
    }
    __syncthreads();
#pragma unroll
    for (int it = 0; it < 4; it++) {
        int idx = it * 256 + threadIdx.x;
        int d = idx >> 3, su = idx & 7;
        us8 o;
#pragma unroll
        for (int j = 0; j < 8; j++) o[j] = tile[su * 8 + j][d];
        *(us8*)(vt + ((long)bh * DV_ + d) * S_ + s0 + su * 8) = o;
    }
}

__global__ void zero9_k(int* __restrict__ cnt)
{
    if (threadIdx.x < NE9_) cnt[threadIdx.x] = (threadIdx.x == 8) ? T_ : 0;
}

__global__ void offs_k(const int* __restrict__ cnt, int* __restrict__ off)
{
    if (threadIdx.x == 0) {
        int a = 0;
        for (int e = 0; e < NE9_; e++) { off[e] = a; a += cnt[e]; }
    }
}

// router: top-2-of-grouped-8 scatter lists + per-token (e,p,w) records
// + identity entry for shared expert (e=8)
__global__ __launch_bounds__(64) void router_k(
    const float* __restrict__ h, const float* __restrict__ rw,
    const float* __restrict__ rb, int* __restrict__ cnt,
    int* __restrict__ idxl, int* __restrict__ tep, float* __restrict__ tww)
{
    int t = blockIdx.x;
    int l = threadIdx.x;
    const float* hr = h + (long)t * H_;
    float pe[8] = {0, 0, 0, 0, 0, 0, 0, 0};
    for (int k = l; k < H_; k += 64) {
        float hv = hr[k];
#pragma unroll
        for (int e = 0; e < 8; e++) pe[e] += hv * rw[e * H_ + k];
    }
#pragma unroll
    for (int e = 0; e < 8; e++)
        for (int o = 32; o; o >>= 1) pe[e] += __shfl_down(pe[e], o);
    if (l == 0) {
        float sr[8], sc[8];
#pragma unroll
        for (int e = 0; e < 8; e++) {
            sr[e] = 1.f / (1.f + __expf(-pe[e]));
            sc[e] = sr[e] + rb[e];
        }
        float gs[4];
        for (int g = 0; g < 4; g++) gs[g] = sc[2 * g] + sc[2 * g + 1];
        int g0 = 0;
        for (int g = 1; g < 4; g++) if (gs[g] > gs[g0]) g0 = g;
        int g1 = -1;
        for (int g = 0; g < 4; g++) {
            if (g == g0) continue;
            if (g1 < 0 || gs[g] > gs[g1]) g1 = g;
        }
        int i0 = -1, i1 = -1;
        for (int e = 0; e < 8; e++) {
            int g = e >> 1;
            if (g != g0 && g != g1) continue;
            if (i0 < 0 || sc[e] > sc[i0]) i0 = e;
        }
        for (int e = 0; e < 8; e++) {
            int g = e >> 1;
            if (g != g0 && g != g1) continue;
            if (e == i0) continue;
            if (i1 < 0 || sc[e] > sc[i1]) i1 = e;
        }
        float w0 = sr[i0], w1 = sr[i1];
        float inv = 2.5f / (w0 + w1 + 1e-20f);
        int p0 = atomicAdd(&cnt[i0], 1);
        idxl[i0 * T_ + p0] = t;
        int p1 = atomicAdd(&cnt[i1], 1);
        idxl[i1 * T_ + p1] = t;
        tep[t * 4 + 0] = i0; tep[t * 4 + 1] = p0;
        tep[t * 4 + 2] = i1; tep[t * 4 + 3] = p1;
        tww[t * 2 + 0] = w0 * inv;
        tww[t * 2 + 1] = w1 * inv;
        idxl[8 * T_ + t] = t;      // shared expert: identity list
    }
}

// out[t] += pd[shared_t] + w0*pd[pos0] + w1*pd[pos1]
__global__ __launch_bounds__(256) void gather_k(
    const unsigned short* __restrict__ pd, const int* __restrict__ off,
    const int* __restrict__ tep, const float* __restrict__ tww,
    float* __restrict__ out)
{
    int t = blockIdx.x;
    int e0 = tep[t * 4], p0 = tep[t * 4 + 1];
    int e1 = tep[t * 4 + 2], p1 = tep[t * 4 + 3];
    float w0 = tww[t * 2], w1 = tww[t * 2 + 1];
    long r0 = (long)(off[e0] + p0) * H_;
    long r1 = (long)(off[e1] + p1) * H_;
    long rs = (long)(off[8] + t) * H_;
    int c = threadIdx.x * 8;
    us8 a = *(const us8*)(pd + r0 + c);
    us8 b = *(const us8*)(pd + r1 + c);
    us8 s = *(const us8*)(pd + rs + c);
    float* op = out + (long)t * H_ + c;
#pragma unroll
    for (int j = 0; j < 8; j++)
        op[j] += bf2f(s[j]) + w0 * bf2f(a[j]) + w1 * bf2f(b[j]);
}

// ---------------------------------------------------------------------------
extern "C" void kernel_launch(void* const* d_in, const int* in_sizes, int n_in,
                              void* d_out, int out_size, void* d_ws, size_t ws_size,
                              hipStream_t stream)
{
    const float* hidden = (const float*)d_in[0];
    const float* cosb   = (const float*)d_in[1];
    const float* sinb   = (const float*)d_in[2];
    const float* ln1w   = (const float*)d_in[3];
    const float* qaw    = (const float*)d_in[4];
    const float* qalnw  = (const float*)d_in[5];
    const float* qbw    = (const float*)d_in[6];
    const float* kvaw   = (const float*)d_in[7];
    const float* kvalnw = (const float*)d_in[8];
    const float* kvbw   = (const float*)d_in[9];
    const float* ow     = (const float*)d_in[10];
    const float* ln2w   = (const float*)d_in[11];
    const float* rw     = (const float*)d_in[12];
    const float* rb     = (const float*)d_in[13];
    const float* gw     = (const float*)d_in[14];
    const float* uw     = (const float*)d_in[15];
    const float* dwn    = (const float*)d_in[16];
    const float* sgw    = (const float*)d_in[17];
    const float* suw    = (const float*)d_in[18];
    const float* sdw    = (const float*)d_in[19];
    float* out = (float*)d_out;
    (void)in_sizes; (void)n_in; (void)out_size; (void)ws_size;

    char* ws = (char*)d_ws;
    const size_t MB = 1u << 20;
    // ---- phase A (attention), MiB offsets ----
    unsigned short* qkawb = (unsigned short*)(ws + 0 * MB);   // 8.5 (2176x2048)
    unsigned short* xb    = (unsigned short*)(ws + 30 * MB);  // 8
    unsigned short* qkab  = (unsigned short*)(ws + 38 * MB);  // 8.5 (T x 2176)
    unsigned short* qb16  = (unsigned short*)(ws + 47 * MB);  // 12
    unsigned short* ckvnb = (unsigned short*)(ws + 59 * MB);  // 2
    unsigned short* kvb   = (unsigned short*)(ws + 61 * MB);  // 16
    unsigned short* qs    = (unsigned short*)(ws + 77 * MB);  // 12
    unsigned short* ks    = (unsigned short*)(ws + 89 * MB);  // 12
    unsigned short* vt    = (unsigned short*)(ws + 30 * MB);  // 8  (alias xb)
    unsigned short* ab    = (unsigned short*)(ws + 38 * MB);  // 8  (alias qkab, dead by FA)
    // ---- phase B (MoE) ----
    float* hbuf = (float*)(ws + 0 * MB);                      // 16 (dead after router)
    unsigned short* actm = (unsigned short*)(ws + 0 * MB);    // 9.4 (6144x768, after router)
    unsigned short* hb16 = (unsigned short*)(ws + 16 * MB);   // 8
    int*   cnt  = (int*)(ws + 24 * MB);
    int*   offb = (int*)(ws + 24 * MB + 256);
    int*   idxl = (int*)(ws + 24 * MB + 512);                 // 72 KB (9 x T)
    int*   tep  = (int*)(ws + 24 * MB + 512 + 9 * T_ * 4);    // 32 KB
    float* tww  = (float*)(ws + 24 * MB + 512 + 9 * T_ * 4 + 4 * T_ * 4); // 16 KB
    unsigned short* pd   = (unsigned short*)(ws + 25 * MB);   // 24 (6144x2048 bf16)

    // ---- merged q_a|kv_a weight (needs concat+pad -> keep cvt) ----
    cvt_qka_k<<<(QKA_ * H_) / 2048, 256, 0, stream>>>(qaw, kvaw, qkawb);

    // ---- attention projections ----
    rmsnorm_f2b<<<T_, 256, 0, stream>>>(hidden, ln1w, xb, nullptr);

    gemm2<0, 0><<<dim3(T_ / 128, QKA_ / 128, 1), 256, 0, stream>>>(
        xb, qkawb, nullptr, nullptr, qkab, nullptr, nullptr, nullptr,
        T_, QKA_, H_, H_, 0);
    rmsnorm_b2b<<<T_, 256, 0, stream>>>(qkab, qalnw, qkab, QL_, QKA_, QKA_);
    gemm2<0, 1><<<dim3(T_ / 128, (NH_ * DQK_) / 128, 1), 256, 0, stream>>>(
        qkab, qbw, nullptr, nullptr, qb16, nullptr, nullptr, nullptr,
        T_, NH_ * DQK_, QL_, QKA_, 0);
    rmsnorm_b2b<<<T_, 256, 0, stream>>>(qkab + QL_, kvalnw, ckvnb, KVL_, QKA_, KVL_);
    gemm2<0, 1><<<dim3(T_ / 128, (NH_ * 256) / 128, 1), 256, 0, stream>>>(
        ckvnb, kvbw, nullptr, nullptr, kvb, nullptr, nullptr, nullptr,
        T_, NH_ * 256, KVL_, KVL_, 0);

    // ---- assemble qs / ks / vt ----
    rope_q_k<<<T_ * NH_, 64, 0, stream>>>(qb16, cosb, sinb, qs);
    rope_k_k<<<T_, 64, 0, stream>>>(qkab, cosb, sinb, ks);
    kpass_k<<<T_ * NH_, 128, 0, stream>>>(kvb, ks);
    vt_k<<<dim3(S_ / 64, B_ * NH_), 256, 0, stream>>>(kvb, vt);

    // ---- flash attention (causal-balanced) ----
    fa_k<<<dim3(S_ / 64, B_ * NH_), 256, 0, stream>>>(qs, ks, vt, ab);

    // ---- o-proj + residual: out = attn @ ow^T + hidden ----
    gemm2<0, 1><<<dim3(T_ / 128, H_ / 128, 1), 256, 0, stream>>>(
        ab, ow, nullptr, out, nullptr, hidden, nullptr, nullptr,
        T_, H_, H_, H_, 0);

    // ---- MoE prep ----
    rmsnorm_f2b<<<T_, 256, 0, stream>>>(out, ln2w, hb16, hbuf);
    zero9_k<<<1, 64, 0, stream>>>(cnt);
    router_k<<<T_, 64, 0, stream>>>(hbuf, rw, rb, cnt, idxl, tep, tww);
    offs_k<<<1, 64, 0, stream>>>(cnt, offb);

    // ---- 9-expert fused gate+up+silu (direct fp32 weights) -> actm ----
    gemm_gu<<<dim3(T_ / 64, INTER_ / 64, NE9_), 256, 0, stream>>>(
        hb16, gw, uw, sgw, suw, actm, cnt, offb, idxl);

    // ---- all 9 experts down (direct fp32 weights) -> bf16 partials ----
    gemm2<2, 1><<<dim3(T_ / 128, H_ / 128, NE9_), 256, 0, stream>>>(
        actm, dwn, sdw, nullptr, pd, nullptr, cnt, offb,
        T_, H_, INTER_, INTER_, (long)H_ * INTER_);
    gather_k<<<T_, 256, 0, stream>>>(pd, offb, tep, tww, out);
}

// Round 14
// 489.630 us; speedup vs baseline: 1.1057x; 1.1057x over previous
//
#include <hip/hip_runtime.h>

typedef float f4 __attribute__((ext_vector_type(4)));
typedef float f32x4 __attribute__((ext_vector_type(4)));
typedef unsigned short us8 __attribute__((ext_vector_type(8)));
typedef __bf16 bf8 __attribute__((ext_vector_type(8)));

static constexpr int B_ = 2, S_ = 1024, H_ = 2048, T_ = B_ * S_;
static constexpr int NH_ = 16, DN_ = 128, DR_ = 64, DV_ = 128, DQK_ = 192;
static constexpr int KVL_ = 512, QL_ = 1536, INTER_ = 768, NEXP_ = 8, NE9_ = 9;
static constexpr int QKA_ = 2176;  // 1536 (q_a) + 576 (kv_a) + 64 pad
static constexpr float SCALING_ = 0.07216878364870322f; // 192^-0.5
static constexpr float EPS_ = 1e-6f;

__device__ __forceinline__ unsigned short f2bf(float f) {
    unsigned u = __float_as_uint(f);
    u += 0x7fffu + ((u >> 16) & 1u);
    return (unsigned short)(u >> 16);
}
__device__ __forceinline__ float bf2f(unsigned short h) {
    return __uint_as_float(((unsigned)h) << 16);
}
__device__ __forceinline__ us8 pack8(f4 a, f4 b) {
    us8 r;
    r[0] = f2bf(a[0]); r[1] = f2bf(a[1]); r[2] = f2bf(a[2]); r[3] = f2bf(a[3]);
    r[4] = f2bf(b[0]); r[5] = f2bf(b[1]); r[6] = f2bf(b[2]); r[7] = f2bf(b[3]);
    return r;
}

// async 16B/lane global->LDS. LDS dest = wave-uniform base + lane*16 (HW).
__device__ __forceinline__ void gload16(const unsigned short* g, unsigned short* lds) {
    __builtin_amdgcn_global_load_lds(
        (const __attribute__((address_space(1))) void*)g,
        (__attribute__((address_space(3))) void*)lds, 16, 0, 0);
}

// ---------------------------------------------------------------------------
// gemm2: C[M,N] = A[M,K] * B[N,K]^T, bf16 in, 128x128 tile, BK=64.
// 2-buffer counted pipeline: stage(t+1) -> vmcnt(8) -> bar -> compute(t) -> bar.
// Chunk-XOR swizzled LDS via pre-swizzled global source (r9-verified, 0 confl).
// MODE 0: plain. Cb -> bf16; else Cf (+add, may alias Cf) fp32.
// MODE 2: A rows compacted at off[e] (z=expert), C bf16 compacted rows.
// ---------------------------------------------------------------------------
template <int MODE>
__global__ __launch_bounds__(256) void gemm2(
    const unsigned short* __restrict__ A, const unsigned short* __restrict__ Bw,
    float* __restrict__ Cf, unsigned short* __restrict__ Cb,
    const float* __restrict__ add,
    const int* __restrict__ cnt, const int* __restrict__ off,
    int M, int N, int K, int ldA, long sB)
{
    constexpr int BM = 128, BN = 128, BK = 64;
    __shared__ __align__(16) unsigned short As[2][BM * BK];
    __shared__ __align__(16) unsigned short Bs[2][BN * BK];
    const int tid = threadIdx.x, lane = tid & 63, wv = tid >> 6;
    const int wm = (wv >> 1) * 64, wn = (wv & 1) * 64;

    const int nb = gridDim.x * gridDim.y;
    const int lin = blockIdx.y * gridDim.x + blockIdx.x;
    const int swz = (lin & 7) * (nb >> 3) + (lin >> 3);
    const int bx = swz % gridDim.x;
    const int by = swz / gridDim.x;
    const int m0 = bx * BM, n0 = by * BN;

    int mcnt = M, obase = 0;
    if constexpr (MODE == 2) {
        mcnt = cnt[blockIdx.z];
        if (m0 >= mcnt) return;
        obase = off[blockIdx.z];
    }

    const int srow = tid >> 3;                       // 0..31 within site
    const int scol = (((tid & 7) ^ (srow & 7)) * 8); // pre-swizzled global col
    long aoff[4], boff[4];
#pragma unroll
    for (int s = 0; s < 4; s++) {
        int r = m0 + s * 32 + srow;
        if constexpr (MODE == 2) {
            aoff[s] = (long)(obase + r) * ldA + scol;
        } else {
            aoff[s] = (long)r * ldA + scol;
        }
        boff[s] = (long)blockIdx.z * sB + (long)(n0 + s * 32 + srow) * K + scol;
    }

    f32x4 acc[4][4];
#pragma unroll
    for (int m = 0; m < 4; m++)
#pragma unroll
        for (int n = 0; n < 4; n++) acc[m][n] = f32x4{0.f, 0.f, 0.f, 0.f};

    const int fr = lane & 15, lg = lane >> 4;
    const int xr = fr & 7;

    auto stage = [&](int buf, int k0) {
#pragma unroll
        for (int s = 0; s < 4; s++)
            gload16(A + aoff[s] + k0, &As[buf][s * 2048 + wv * 512]);
#pragma unroll
        for (int s = 0; s < 4; s++)
            gload16(Bw + boff[s] + k0, &Bs[buf][s * 2048 + wv * 512]);
    };
    auto compute = [&](int buf) {
        __builtin_amdgcn_s_setprio(1);
        bf8 af[4][2], bfv[4][2];
#pragma unroll
        for (int m = 0; m < 4; m++) {
            int R = wm + m * 16 + fr;
#pragma unroll
            for (int ks = 0; ks < 2; ks++)
                af[m][ks] = *(const bf8*)&As[buf][R * 64 + ((ks * 4 + lg) ^ xr) * 8];
        }
#pragma unroll
        for (int n = 0; n < 4; n++) {
            int R = wn + n * 16 + fr;
#pragma unroll
            for (int ks = 0; ks < 2; ks++)
                bfv[n][ks] = *(const bf8*)&Bs[buf][R * 64 + ((ks * 4 + lg) ^ xr) * 8];
        }
#pragma unroll
        for (int m = 0; m < 4; m++)
#pragma unroll
            for (int n = 0; n < 4; n++) {
                acc[m][n] = __builtin_amdgcn_mfma_f32_16x16x32_bf16(af[m][0], bfv[n][0], acc[m][n], 0, 0, 0);
                acc[m][n] = __builtin_amdgcn_mfma_f32_16x16x32_bf16(af[m][1], bfv[n][1], acc[m][n], 0, 0, 0);
            }
        __builtin_amdgcn_s_setprio(0);
    };

    const int nt = K / BK;
    stage(0, 0);
    for (int t = 0; t < nt; t++) {
        if (t + 1 < nt) {
            stage((t & 1) ^ 1, (t + 1) * BK);
            asm volatile("s_waitcnt vmcnt(8)" ::: "memory");
        } else {
            asm volatile("s_waitcnt vmcnt(0)" ::: "memory");
        }
        __builtin_amdgcn_s_barrier();
        compute(t & 1);
        __builtin_amdgcn_s_barrier();
    }

#pragma unroll
    for (int m = 0; m < 4; m++) {
#pragma unroll
        for (int n = 0; n < 4; n++) {
#pragma unroll
            for (int i = 0; i < 4; i++) {
                int row = wm + m * 16 + lg * 4 + i;
                int col = n0 + wn + n * 16 + fr;
                float v = acc[m][n][i];
                if constexpr (MODE == 0) {
                    long idx = (long)(m0 + row) * N + col;
                    if (Cb)       Cb[idx] = f2bf(v);
                    else if (add) Cf[idx] = v + add[idx];
                    else          Cf[idx] = v;
                } else {
                    if (m0 + row < mcnt)
                        Cb[(long)(obase + m0 + row) * N + col] = f2bf(v);
                }
            }
        }
    }
}

// ---------------------------------------------------------------------------
// gemm_gu: fused MoE gate+up+silu, BM=64, BN=64 (+64 up). LDS 48 KB ->
// 3 blocks/CU (12 waves). Rows gathered via idxl[z]; epilogue writes
// actm = bf16(silu(g)*u) compacted at off[z]. 6 loads/thread -> vmcnt(6).
// ---------------------------------------------------------------------------
__global__ __launch_bounds__(256) void gemm_gu(
    const unsigned short* __restrict__ A, const unsigned short* __restrict__ Bw,
    unsigned short* __restrict__ actm,
    const int* __restrict__ cnt, const int* __restrict__ off,
    const int* __restrict__ idxl)
{
    constexpr int BM = 64, BN = 64, BK = 64, K = H_;
    __shared__ __align__(16) unsigned short As[2][BM * BK];   // 8 KB x2
    __shared__ __align__(16) unsigned short Bg[2][BN * BK];   // 8 KB x2
    __shared__ __align__(16) unsigned short Bu[2][BN * BK];   // 8 KB x2
    const int tid = threadIdx.x, lane = tid & 63, wv = tid >> 6;
    const int wm = (wv >> 1) * 32, wn = (wv & 1) * 32;

    const int nb = gridDim.x * gridDim.y;     // 32*12=384, %8==0
    const int lin = blockIdx.y * gridDim.x + blockIdx.x;
    const int swz = (lin & 7) * (nb >> 3) + (lin >> 3);
    const int bx = swz % gridDim.x;
    const int by = swz / gridDim.x;
    const int m0 = bx * BM, n0 = by * BN;
    const int e = blockIdx.z;

    const int mcnt = cnt[e];
    if (m0 >= mcnt) return;
    const int obase = off[e];

    const int srow = tid >> 3;
    const int scol = (((tid & 7) ^ (srow & 7)) * 8);
    long aoff[2], bgo[2], buo[2];
#pragma unroll
    for (int s = 0; s < 2; s++) {
        int r = m0 + s * 32 + srow;
        int rc = (r < mcnt) ? r : mcnt - 1;
        aoff[s] = (long)idxl[(long)e * T_ + rc] * H_ + scol;
        bgo[s] = ((long)e * (2 * INTER_) + n0 + s * 32 + srow) * K + scol;
        buo[s] = ((long)e * (2 * INTER_) + INTER_ + n0 + s * 32 + srow) * K + scol;
    }

    f32x4 ag[2][2], au[2][2];
#pragma unroll
    for (int m = 0; m < 2; m++)
#pragma unroll
        for (int n = 0; n < 2; n++) {
            ag[m][n] = f32x4{0.f, 0.f, 0.f, 0.f};
            au[m][n] = f32x4{0.f, 0.f, 0.f, 0.f};
        }

    const int fr = lane & 15, lg = lane >> 4;
    const int xr = fr & 7;

    auto stage = [&](int buf, int k0) {
#pragma unroll
        for (int s = 0; s < 2; s++)
            gload16(A + aoff[s] + k0, &As[buf][s * 2048 + wv * 512]);
#pragma unroll
        for (int s = 0; s < 2; s++)
            gload16(Bw + bgo[s] + k0, &Bg[buf][s * 2048 + wv * 512]);
#pragma unroll
        for (int s = 0; s < 2; s++)
            gload16(Bw + buo[s] + k0, &Bu[buf][s * 2048 + wv * 512]);
    };
    auto compute = [&](int buf) {
        __builtin_amdgcn_s_setprio(1);
        bf8 af[2][2], bgf[2][2], buf_[2][2];
#pragma unroll
        for (int m = 0; m < 2; m++) {
            int R = wm + m * 16 + fr;
#pragma unroll
            for (int ks = 0; ks < 2; ks++)
                af[m][ks] = *(const bf8*)&As[buf][R * 64 + ((ks * 4 + lg) ^ xr) * 8];
        }
#pragma unroll
        for (int n = 0; n < 2; n++) {
            int R = wn + n * 16 + fr;
#pragma unroll
            for (int ks = 0; ks < 2; ks++) {
                bgf[n][ks] = *(const bf8*)&Bg[buf][R * 64 + ((ks * 4 + lg) ^ xr) * 8];
                buf_[n][ks] = *(const bf8*)&Bu[buf][R * 64 + ((ks * 4 + lg) ^ xr) * 8];
            }
        }
#pragma unroll
        for (int m = 0; m < 2; m++)
#pragma unroll
            for (int n = 0; n < 2; n++) {
                ag[m][n] = __builtin_amdgcn_mfma_f32_16x16x32_bf16(af[m][0], bgf[n][0], ag[m][n], 0, 0, 0);
                ag[m][n] = __builtin_amdgcn_mfma_f32_16x16x32_bf16(af[m][1], bgf[n][1], ag[m][n], 0, 0, 0);
                au[m][n] = __builtin_amdgcn_mfma_f32_16x16x32_bf16(af[m][0], buf_[n][0], au[m][n], 0, 0, 0);
                au[m][n] = __builtin_amdgcn_mfma_f32_16x16x32_bf16(af[m][1], buf_[n][1], au[m][n], 0, 0, 0);
            }
        __builtin_amdgcn_s_setprio(0);
    };

    const int nt = K / BK;   // 32
    stage(0, 0);
    for (int t = 0; t < nt; t++) {
        if (t + 1 < nt) {
            stage((t & 1) ^ 1, (t + 1) * BK);
            asm volatile("s_waitcnt vmcnt(6)" ::: "memory");
        } else {
            asm volatile("s_waitcnt vmcnt(0)" ::: "memory");
        }
        __builtin_amdgcn_s_barrier();
        compute(t & 1);
        __builtin_amdgcn_s_barrier();
    }

#pragma unroll
    for (int m = 0; m < 2; m++) {
#pragma unroll
        for (int n = 0; n < 2; n++) {
#pragma unroll
            for (int i = 0; i < 4; i++) {
                int row = wm + m * 16 + lg * 4 + i;
                if (m0 + row < mcnt) {
                    float g = ag[m][n][i], u = au[m][n][i];
                    float v = g / (1.f + __expf(-g)) * u;
                    actm[(long)(obase + m0 + row) * INTER_ + n0 + wn + n * 16 + fr] = f2bf(v);
                }
            }
        }
    }
}

// ---------------------------------------------------------------------------
// Flash attention (causal). grid (S/64, B*NH), 256 threads (4 waves).
// q-tile index reversed for heads y>=16 so co-resident block pairs have
// complementary causal workloads (x, 15-x) -> balanced CUs.
// ---------------------------------------------------------------------------
__global__ __launch_bounds__(256) void fa_k(
    const unsigned short* __restrict__ qs, const unsigned short* __restrict__ ks,
    const unsigned short* __restrict__ vt, unsigned short* __restrict__ ab)
{
    constexpr int KB = 64;
    const int qx = (blockIdx.y & 16) ? (gridDim.x - 1 - (int)blockIdx.x) : (int)blockIdx.x;
    const int q0 = qx * 64;
    const int bh = blockIdx.y;
    const int b = bh >> 4, h = bh & 15;
    const int tid = threadIdx.x, lane = tid & 63, wv = tid >> 6;
    const int fr = lane & 15, lg = lane >> 4;
    const int ko = lg * 8;

    __shared__ __align__(16) unsigned short Kl[KB][200];
    __shared__ __align__(16) unsigned short Vl[128][72];
    __shared__ __align__(16) unsigned short Pl[4][16][72];

    const unsigned short* qp = qs + ((long)bh * S_ + q0 + wv * 16 + fr) * DQK_ + ko;
    bf8 qf[6];
#pragma unroll
    for (int s = 0; s < 6; s++) qf[s] = *(const bf8*)(qp + s * 32);

    f32x4 o[8];
#pragma unroll
    for (int n = 0; n < 8; n++) o[n] = f32x4{0.f, 0.f, 0.f, 0.f};
    float mrow[4] = {-3e38f, -3e38f, -3e38f, -3e38f};
    float lrow[4] = {0.f, 0.f, 0.f, 0.f};

    const int nt = q0 / KB + 1;

    const unsigned short* kg = ks + ((long)bh * S_ + (tid >> 2)) * DQK_ + (tid & 3) * 48;
    const unsigned short* vg = vt + ((long)bh * DV_ + (tid >> 1)) * S_ + (tid & 1) * 32;

    us8 krg[6], vrg[4];
#pragma unroll
    for (int j = 0; j < 6; j++) krg[j] = *(const us8*)(kg + j * 8);
#pragma unroll
    for (int j = 0; j < 4; j++) vrg[j] = *(const us8*)(vg + j * 8);

    for (int t = 0; t < nt; t++) {
        __syncthreads();
        {
            int r = tid >> 2, c = (tid & 3) * 48;
#pragma unroll
            for (int j = 0; j < 6; j++) *(us8*)&Kl[r][c + j * 8] = krg[j];
            int dv = tid >> 1, c2 = (tid & 1) * 32;
#pragma unroll
            for (int j = 0; j < 4; j++) *(us8*)&Vl[dv][c2 + j * 8] = vrg[j];
        }
        __syncthreads();
        if (t + 1 < nt) {
            long kof = (long)(t + 1) * KB;
#pragma unroll
            for (int j = 0; j < 6; j++) krg[j] = *(const us8*)(kg + kof * DQK_ + j * 8);
#pragma unroll
            for (int j = 0; j < 4; j++) vrg[j] = *(const us8*)(vg + kof + j * 8);
        }
        f32x4 ps[4];
#pragma unroll
        for (int ct = 0; ct < 4; ct++) {
            f32x4 a = f32x4{0.f, 0.f, 0.f, 0.f};
#pragma unroll
            for (int s = 0; s < 6; s++) {
                bf8 kf = *(const bf8*)&Kl[ct * 16 + fr][s * 32 + ko];
                a = __builtin_amdgcn_mfma_f32_16x16x32_bf16(qf[s], kf, a, 0, 0, 0);
            }
            ps[ct] = a;
        }
        const int kv0 = t * KB;
        const bool diag = (kv0 == q0);
#pragma unroll
        for (int ct = 0; ct < 4; ct++)
#pragma unroll
            for (int i = 0; i < 4; i++) {
                float v = ps[ct][i] * SCALING_;
                if (diag && (kv0 + ct * 16 + fr) > (q0 + wv * 16 + lg * 4 + i)) v = -3e38f;
                ps[ct][i] = v;
            }
        float scl[4];
#pragma unroll
        for (int i = 0; i < 4; i++) {
            float v = fmaxf(fmaxf(ps[0][i], ps[1][i]), fmaxf(ps[2][i], ps[3][i]));
#pragma unroll
            for (int x = 8; x; x >>= 1) v = fmaxf(v, __shfl_xor(v, x, 16));
            float mn = fmaxf(mrow[i], v);
            scl[i] = __expf(mrow[i] - mn);
            mrow[i] = mn;
        }
        float tsum[4] = {0.f, 0.f, 0.f, 0.f};
#pragma unroll
        for (int ct = 0; ct < 4; ct++)
#pragma unroll
            for (int i = 0; i < 4; i++) {
                float e = __expf(ps[ct][i] - mrow[i]);
                tsum[i] += e;
                Pl[wv][lg * 4 + i][ct * 16 + fr] = f2bf(e);
            }
#pragma unroll
        for (int i = 0; i < 4; i++) {
            float v = tsum[i];
#pragma unroll
            for (int x = 8; x; x >>= 1) v += __shfl_xor(v, x, 16);
            lrow[i] = lrow[i] * scl[i] + v;
        }
#pragma unroll
        for (int n = 0; n < 8; n++)
#pragma unroll
            for (int i = 0; i < 4; i++) o[n][i] *= scl[i];
        bf8 pf[2];
#pragma unroll
        for (int ksl = 0; ksl < 2; ksl++)
            pf[ksl] = *(const bf8*)&Pl[wv][fr][ksl * 32 + ko];
#pragma unroll
        for (int n = 0; n < 8; n++)
#pragma unroll
            for (int ksl = 0; ksl < 2; ksl++) {
                bf8 vf = *(const bf8*)&Vl[n * 16 + fr][ksl * 32 + ko];
                o[n] = __builtin_amdgcn_mfma_f32_16x16x32_bf16(pf[ksl], vf, o[n], 0, 0, 0);
            }
    }
#pragma unroll
    for (int i = 0; i < 4; i++) {
        float inv = 1.f / lrow[i];
        long rbase = ((long)b * S_ + q0 + wv * 16 + lg * 4 + i) * H_ + h * DV_;
#pragma unroll
        for (int n = 0; n < 8; n++)
            ab[rbase + n * 16 + fr] = f2bf(o[n][i] * inv);
    }
}

// ---------------------------------------------------------------------------
// conversion kernels (fp32 -> bf16), 8 elems/thread
// ---------------------------------------------------------------------------
__global__ __launch_bounds__(256) void cvt_k(
    const float* __restrict__ s, unsigned short* __restrict__ d, long n)
{
    long i = ((long)blockIdx.x * 256 + threadIdx.x) * 8;
    if (i < n) {
        f4 a = *(const f4*)(s + i);
        f4 b = *(const f4*)(s + i + 4);
        *(us8*)(d + i) = pack8(a, b);
    }
}

// merged q_a|kv_a weights: rows [0,1536)=qaw, [1536,2112)=kvaw, [2112,2176)=0
__global__ __launch_bounds__(256) void cvt_qka_k(
    const float* __restrict__ qa, const float* __restrict__ kva,
    unsigned short* __restrict__ d)
{
    long i = ((long)blockIdx.x * 256 + threadIdx.x) * 8;   // over 2176*2048
    long row = i >> 11, col = i & 2047;
    us8 o;
    if (row < QL_) {
        const float* s = qa + row * H_ + col;
        o = pack8(*(const f4*)s, *(const f4*)(s + 4));
    } else if (row < QL_ + 576) {
        const float* s = kva + (row - QL_) * H_ + col;
        o = pack8(*(const f4*)s, *(const f4*)(s + 4));
    } else {
        o = us8{0, 0, 0, 0, 0, 0, 0, 0};
    }
    *(us8*)(d + i) = o;
}

// 9-expert gate|up concat: z<8 routed (gw/uw), z==8 shared (sgw/suw)
__global__ __launch_bounds__(256) void cvt_cat9_k(
    const float* __restrict__ g, const float* __restrict__ u,
    const float* __restrict__ sg, const float* __restrict__ su,
    unsigned short* __restrict__ d)
{
    long ii = ((long)blockIdx.x * 256 + threadIdx.x) * 8;   // 1536*2048 per expert
    int e = blockIdx.y;
    long row = ii >> 11, col = ii & 2047;
    const float* src;
    if (row < INTER_)
        src = (e < 8) ? (g + ((long)e * INTER_ + row) * H_ + col) : (sg + row * H_ + col);
    else
        src = (e < 8) ? (u + ((long)e * INTER_ + row - INTER_) * H_ + col)
                      : (su + (row - INTER_) * H_ + col);
    *(us8*)(d + (long)e * (2 * INTER_) * H_ + ii) = pack8(*(const f4*)src, *(const f4*)(src + 4));
}

// ---------------------------------------------------------------------------
// rmsnorm fp32->bf16 (+ optional fp32 copy); cols == H_ == 2048 (8/thread)
__global__ __launch_bounds__(256) void rmsnorm_f2b(
    const float* __restrict__ in, const float* __restrict__ w,
    unsigned short* __restrict__ ob, float* __restrict__ of)
{
    const long base = (long)blockIdx.x * H_;
    const int c = threadIdx.x * 8;
    f4 v0 = *(const f4*)(in + base + c);
    f4 v1 = *(const f4*)(in + base + c + 4);
    float ss = v0[0] * v0[0] + v0[1] * v0[1] + v0[2] * v0[2] + v0[3] * v0[3]
             + v1[0] * v1[0] + v1[1] * v1[1] + v1[2] * v1[2] + v1[3] * v1[3];
#pragma unroll
    for (int o = 32; o; o >>= 1) ss += __shfl_down(ss, o);
    __shared__ float red[4];
    if ((threadIdx.x & 63) == 0) red[threadIdx.x >> 6] = ss;
    __syncthreads();
    float r = rsqrtf((red[0] + red[1] + red[2] + red[3]) / H_ + EPS_);
    f4 w0 = *(const f4*)(w + c);
    f4 w1 = *(const f4*)(w + c + 4);
    f4 a, b;
#pragma unroll
    for (int j = 0; j < 4; j++) { a[j] = v0[j] * r * w0[j]; b[j] = v1[j] * r * w1[j]; }
    *(us8*)(ob + base + c) = pack8(a, b);
    if (of) {
        *(f4*)(of + base + c) = a;
        *(f4*)(of + base + c + 4) = b;
    }
}

// bf16 in (istride) -> bf16 out (ostride); in==out safe (per-thread RBW)
__global__ __launch_bounds__(256) void rmsnorm_b2b(
    const unsigned short* __restrict__ in, const float* __restrict__ w,
    unsigned short* __restrict__ out, int cols, int istride, int ostride)
{
    const long ib = (long)blockIdx.x * istride;
    const long ob = (long)blockIdx.x * ostride;
    const int nu = cols >> 3;
    float ss = 0.f;
    for (int u = threadIdx.x; u < nu; u += 256) {
        us8 v = *(const us8*)(in + ib + u * 8);
#pragma unroll
        for (int j = 0; j < 8; j++) { float f = bf2f(v[j]); ss += f * f; }
    }
#pragma unroll
    for (int o = 32; o; o >>= 1) ss += __shfl_down(ss, o);
    __shared__ float red[4];
    if ((threadIdx.x & 63) == 0) red[threadIdx.x >> 6] = ss;
    __syncthreads();
    float r = rsqrtf((red[0] + red[1] + red[2] + red[3]) / cols + EPS_);
    for (int u = threadIdx.x; u < nu; u += 256) {
        us8 v = *(const us8*)(in + ib + u * 8);
        f4 w0 = *(const f4*)(w + u * 8);
        f4 w1 = *(const f4*)(w + u * 8 + 4);
        us8 o;
#pragma unroll
        for (int j = 0; j < 4; j++) o[j] = f2bf(bf2f(v[j]) * r * w0[j]);
#pragma unroll
        for (int j = 0; j < 4; j++) o[4 + j] = f2bf(bf2f(v[4 + j]) * r * w1[j]);
        *(us8*)(out + ob + u * 8) = o;
    }
}

// ---------------------------------------------------------------------------
__global__ __launch_bounds__(64) void rope_q_k(
    const unsigned short* __restrict__ q, const float* __restrict__ cs,
    const float* __restrict__ sn, unsigned short* __restrict__ qs)
{
    int t = blockIdx.x;            // (b*S+s)*16 + h
    int h = t & 15;
    int bs = t >> 4;
    int s = bs & (S_ - 1);
    int b = bs >> 10;
    const unsigned short* qrow = q + (long)bs * (NH_ * DQK_) + h * DQK_;
    unsigned short* orow = qs + ((long)(b * NH_ + h) * S_ + s) * DQK_;
    int l = threadIdx.x;
    orow[l] = qrow[l];
    orow[l + 64] = qrow[l + 64];
    int j = l & 31;
    float x0 = bf2f(qrow[DN_ + 2 * j]), x1 = bf2f(qrow[DN_ + 2 * j + 1]);
    float c = cs[(long)bs * DR_ + j], si = sn[(long)bs * DR_ + j];
    if (l < 32) orow[DN_ + j] = f2bf(x0 * c - x1 * si);
    else        orow[DN_ + 32 + j] = f2bf(x1 * c + x0 * si);
}

// k_rot lives in qkab cols [QL_+512, QL_+576), row stride QKA_
__global__ __launch_bounds__(64) void rope_k_k(
    const unsigned short* __restrict__ qkab, const float* __restrict__ cs,
    const float* __restrict__ sn, unsigned short* __restrict__ ks)
{
    int bs = blockIdx.x;
    int s = bs & (S_ - 1);
    int b = bs >> 10;
    const unsigned short* kr = qkab + (long)bs * QKA_ + QL_ + KVL_;
    int l = threadIdx.x;
    int j = l & 31;
    float x0 = bf2f(kr[2 * j]), x1 = bf2f(kr[2 * j + 1]);
    float c = cs[(long)bs * DR_ + j], si = sn[(long)bs * DR_ + j];
    float val = (l < 32) ? (x0 * c - x1 * si) : (x1 * c + x0 * si);
    int off = (l < 32) ? (DN_ + j) : (DN_ + 32 + j);
    unsigned short bv = f2bf(val);
    for (int h = 0; h < NH_; h++)
        ks[((long)(b * NH_ + h) * S_ + s) * DQK_ + off] = bv;
}

__global__ __launch_bounds__(128) void kpass_k(
    const unsigned short* __restrict__ kv, unsigned short* __restrict__ ks)
{
    int t = blockIdx.x; // (b*S+s)*16 + h
    int h = t & 15;
    int bs = t >> 4;
    int s = bs & (S_ - 1);
    int b = bs >> 10;
    ks[((long)(b * NH_ + h) * S_ + s) * DQK_ + threadIdx.x] = kv[(long)t * 256 + threadIdx.x];
}

// V transpose: kv (B,S,NH,256)[:,128:] -> vt (B,NH,128,S), vectorized
__global__ __launch_bounds__(256) void vt_k(
    const unsigned short* __restrict__ kv, unsigned short* __restrict__ vt)
{
    __shared__ unsigned short tile[64][DV_ + 8];
    int s0 = blockIdx.x * 64;
    int bh = blockIdx.y;
    int b = bh >> 4, h = bh & 15;
#pragma unroll
    for (int it = 0; it < 4; it++) {
        int idx = it * 256 + threadIdx.x;
        int sl = idx >> 4, du = idx & 15;
        *(us8*)&tile[sl][du * 8] =
            *(const us8*)(kv + ((long)(b * S_ + s0 + sl) * NH_ + h) * 256 + DN_ + du * 8);
    }
    __syncthreads();
#pragma unroll
    for (int it = 0; it < 4; it++) {
        int idx = it * 256 + threadIdx.x;
        int d = idx >> 3, su = idx & 7;
        us8 o;
#pragma unroll
        for (int j = 0; j < 8; j++) o[j] = tile[su * 8 + j][d];
        *(us8*)(vt + ((long)bh * DV_ + d) * S_ + s0 + su * 8) = o;
    }
}

__global__ void zero9_k(int* __restrict__ cnt)
{
    if (threadIdx.x < NE9_) cnt[threadIdx.x] = (threadIdx.x == 8) ? T_ : 0;
}

__global__ void offs_k(const int* __restrict__ cnt, int* __restrict__ off)
{
    if (threadIdx.x == 0) {
        int a = 0;
        for (int e = 0; e < NE9_; e++) { off[e] = a; a += cnt[e]; }
    }
}

// router: top-2-of-grouped-8 scatter lists + per-token (e,p,w) records
// + identity entry for shared expert (e=8)
__global__ __launch_bounds__(64) void router_k(
    const float* __restrict__ h, const float* __restrict__ rw,
    const float* __restrict__ rb, int* __restrict__ cnt,
    int* __restrict__ idxl, int* __restrict__ tep, float* __restrict__ tww)
{
    int t = blockIdx.x;
    int l = threadIdx.x;
    const float* hr = h + (long)t * H_;
    float pe[8] = {0, 0, 0, 0, 0, 0, 0, 0};
    for (int k = l; k < H_; k += 64) {
        float hv = hr[k];
#pragma unroll
        for (int e = 0; e < 8; e++) pe[e] += hv * rw[e * H_ + k];
    }
#pragma unroll
    for (int e = 0; e < 8; e++)
        for (int o = 32; o; o >>= 1) pe[e] += __shfl_down(pe[e], o);
    if (l == 0) {
        float sr[8], sc[8];
#pragma unroll
        for (int e = 0; e < 8; e++) {
            sr[e] = 1.f / (1.f + __expf(-pe[e]));
            sc[e] = sr[e] + rb[e];
        }
        float gs[4];
        for (int g = 0; g < 4; g++) gs[g] = sc[2 * g] + sc[2 * g + 1];
        int g0 = 0;
        for (int g = 1; g < 4; g++) if (gs[g] > gs[g0]) g0 = g;
        int g1 = -1;
        for (int g = 0; g < 4; g++) {
            if (g == g0) continue;
            if (g1 < 0 || gs[g] > gs[g1]) g1 = g;
        }
        int i0 = -1, i1 = -1;
        for (int e = 0; e < 8; e++) {
            int g = e >> 1;
            if (g != g0 && g != g1) continue;
            if (i0 < 0 || sc[e] > sc[i0]) i0 = e;
        }
        for (int e = 0; e < 8; e++) {
            int g = e >> 1;
            if (g != g0 && g != g1) continue;
            if (e == i0) continue;
            if (i1 < 0 || sc[e] > sc[i1]) i1 = e;
        }
        float w0 = sr[i0], w1 = sr[i1];
        float inv = 2.5f / (w0 + w1 + 1e-20f);
        int p0 = atomicAdd(&cnt[i0], 1);
        idxl[i0 * T_ + p0] = t;
        int p1 = atomicAdd(&cnt[i1], 1);
        idxl[i1 * T_ + p1] = t;
        tep[t * 4 + 0] = i0; tep[t * 4 + 1] = p0;
        tep[t * 4 + 2] = i1; tep[t * 4 + 3] = p1;
        tww[t * 2 + 0] = w0 * inv;
        tww[t * 2 + 1] = w1 * inv;
        idxl[8 * T_ + t] = t;      // shared expert: identity list
    }
}

// out[t] += pd[shared_t] + w0*pd[pos0] + w1*pd[pos1]
__global__ __launch_bounds__(256) void gather_k(
    const unsigned short* __restrict__ pd, const int* __restrict__ off,
    const int* __restrict__ tep, const float* __restrict__ tww,
    float* __restrict__ out)
{
    int t = blockIdx.x;
    int e0 = tep[t * 4], p0 = tep[t * 4 + 1];
    int e1 = tep[t * 4 + 2], p1 = tep[t * 4 + 3];
    float w0 = tww[t * 2], w1 = tww[t * 2 + 1];
    long r0 = (long)(off[e0] + p0) * H_;
    long r1 = (long)(off[e1] + p1) * H_;
    long rs = (long)(off[8] + t) * H_;
    int c = threadIdx.x * 8;
    us8 a = *(const us8*)(pd + r0 + c);
    us8 b = *(const us8*)(pd + r1 + c);
    us8 s = *(const us8*)(pd + rs + c);
    float* op = out + (long)t * H_ + c;
#pragma unroll
    for (int j = 0; j < 8; j++)
        op[j] += bf2f(s[j]) + w0 * bf2f(a[j]) + w1 * bf2f(b[j]);
}

// ---------------------------------------------------------------------------
extern "C" void kernel_launch(void* const* d_in, const int* in_sizes, int n_in,
                              void* d_out, int out_size, void* d_ws, size_t ws_size,
                              hipStream_t stream)
{
    const float* hidden = (const float*)d_in[0];
    const float* cosb   = (const float*)d_in[1];
    const float* sinb   = (const float*)d_in[2];
    const float* ln1w   = (const float*)d_in[3];
    const float* qaw    = (const float*)d_in[4];
    const float* qalnw  = (const float*)d_in[5];
    const float* qbw    = (const float*)d_in[6];
    const float* kvaw   = (const float*)d_in[7];
    const float* kvalnw = (const float*)d_in[8];
    const float* kvbw   = (const float*)d_in[9];
    const float* ow     = (const float*)d_in[10];
    const float* ln2w   = (const float*)d_in[11];
    const float* rw     = (const float*)d_in[12];
    const float* rb     = (const float*)d_in[13];
    const float* gw     = (const float*)d_in[14];
    const float* uw     = (const float*)d_in[15];
    const float* dwn    = (const float*)d_in[16];
    const float* sgw    = (const float*)d_in[17];
    const float* suw    = (const float*)d_in[18];
    const float* sdw    = (const float*)d_in[19];
    float* out = (float*)d_out;
    (void)in_sizes; (void)n_in; (void)out_size; (void)ws_size;

    char* ws = (char*)d_ws;
    const size_t MB = 1u << 20;
    // ---- phase A (attention), MiB offsets ----
    unsigned short* qkawb = (unsigned short*)(ws + 0 * MB);   // 8.5 (2176x2048)
    unsigned short* qbwb  = (unsigned short*)(ws + 9 * MB);   // 9
    unsigned short* kvbwb = (unsigned short*)(ws + 18 * MB);  // 4
    unsigned short* owb   = (unsigned short*)(ws + 22 * MB);  // 8
    unsigned short* xb    = (unsigned short*)(ws + 30 * MB);  // 8
    unsigned short* qkab  = (unsigned short*)(ws + 38 * MB);  // 8.5 (T x 2176)
    unsigned short* qb16  = (unsigned short*)(ws + 47 * MB);  // 12
    unsigned short* ckvnb = (unsigned short*)(ws + 59 * MB);  // 2
    unsigned short* kvb   = (unsigned short*)(ws + 61 * MB);  // 16
    unsigned short* qs    = (unsigned short*)(ws + 77 * MB);  // 12
    unsigned short* ks    = (unsigned short*)(ws + 89 * MB);  // 12
    unsigned short* vt    = (unsigned short*)(ws + 30 * MB);  // 8  (alias xb)
    unsigned short* ab    = (unsigned short*)(ws + 38 * MB);  // 8  (alias qkab, dead by FA)
    // ---- phase B (MoE) ----
    float* hbuf = (float*)(ws + 0 * MB);                      // 16 (dead after router)
    unsigned short* actm = (unsigned short*)(ws + 0 * MB);    // 9.4 (6144x768, after router)
    unsigned short* hb16 = (unsigned short*)(ws + 16 * MB);   // 8
    int*   cnt  = (int*)(ws + 24 * MB);
    int*   offb = (int*)(ws + 24 * MB + 256);
    int*   idxl = (int*)(ws + 24 * MB + 512);                 // 72 KB (9 x T)
    int*   tep  = (int*)(ws + 24 * MB + 512 + 9 * T_ * 4);    // 32 KB
    float* tww  = (float*)(ws + 24 * MB + 512 + 9 * T_ * 4 + 4 * T_ * 4); // 16 KB
    unsigned short* guwb = (unsigned short*)(ws + 25 * MB);   // 54 (9x1536x2048)
    unsigned short* dwnb = (unsigned short*)(ws + 25 * MB);   // 27 (alias guwb, after gu)
    unsigned short* pd   = (unsigned short*)(ws + 79 * MB);   // 24 (6144x2048 bf16)

    // ---- weight conversion (attention) ----
    cvt_qka_k<<<(QKA_ * H_) / 2048, 256, 0, stream>>>(qaw, kvaw, qkawb);
    cvt_k<<<(NH_ * DQK_ * QL_) / 2048, 256, 0, stream>>>(qbw, qbwb, (long)NH_ * DQK_ * QL_);
    cvt_k<<<(NH_ * 256 * KVL_) / 2048, 256, 0, stream>>>(kvbw, kvbwb, (long)NH_ * 256 * KVL_);
    cvt_k<<<(H_ * H_) / 2048, 256, 0, stream>>>(ow, owb, (long)H_ * H_);

    // ---- attention projections ----
    rmsnorm_f2b<<<T_, 256, 0, stream>>>(hidden, ln1w, xb, nullptr);

    gemm2<0><<<dim3(T_ / 128, QKA_ / 128, 1), 256, 0, stream>>>(
        xb, qkawb, nullptr, qkab, nullptr, nullptr, nullptr,
        T_, QKA_, H_, H_, 0);
    rmsnorm_b2b<<<T_, 256, 0, stream>>>(qkab, qalnw, qkab, QL_, QKA_, QKA_);
    gemm2<0><<<dim3(T_ / 128, (NH_ * DQK_) / 128, 1), 256, 0, stream>>>(
        qkab, qbwb, nullptr, qb16, nullptr, nullptr, nullptr,
        T_, NH_ * DQK_, QL_, QKA_, 0);
    rmsnorm_b2b<<<T_, 256, 0, stream>>>(qkab + QL_, kvalnw, ckvnb, KVL_, QKA_, KVL_);
    gemm2<0><<<dim3(T_ / 128, (NH_ * 256) / 128, 1), 256, 0, stream>>>(
        ckvnb, kvbwb, nullptr, kvb, nullptr, nullptr, nullptr,
        T_, NH_ * 256, KVL_, KVL_, 0);

    // ---- assemble qs / ks / vt ----
    rope_q_k<<<T_ * NH_, 64, 0, stream>>>(qb16, cosb, sinb, qs);
    rope_k_k<<<T_, 64, 0, stream>>>(qkab, cosb, sinb, ks);
    kpass_k<<<T_ * NH_, 128, 0, stream>>>(kvb, ks);
    vt_k<<<dim3(S_ / 64, B_ * NH_), 256, 0, stream>>>(kvb, vt);

    // ---- flash attention (causal-balanced) ----
    fa_k<<<dim3(S_ / 64, B_ * NH_), 256, 0, stream>>>(qs, ks, vt, ab);

    // ---- o-proj + residual: out = attn @ ow^T + hidden ----
    gemm2<0><<<dim3(T_ / 128, H_ / 128, 1), 256, 0, stream>>>(
        ab, owb, out, nullptr, hidden, nullptr, nullptr,
        T_, H_, H_, H_, 0);

    // ---- MoE prep ----
    rmsnorm_f2b<<<T_, 256, 0, stream>>>(out, ln2w, hb16, hbuf);
    zero9_k<<<1, 64, 0, stream>>>(cnt);
    router_k<<<T_, 64, 0, stream>>>(hbuf, rw, rb, cnt, idxl, tep, tww);
    offs_k<<<1, 64, 0, stream>>>(cnt, offb);

    // ---- 9-expert fused gate+up+silu -> actm (compacted bf16) ----
    cvt_cat9_k<<<dim3((2 * INTER_ * H_) / 2048, NE9_), 256, 0, stream>>>(gw, uw, sgw, suw, guwb);
    gemm_gu<<<dim3(T_ / 64, INTER_ / 64, NE9_), 256, 0, stream>>>(
        hb16, guwb, actm, cnt, offb, idxl);

    // ---- down weights (routed 0..7 then shared at index 8) ----
    cvt_k<<<(NEXP_ * H_ * INTER_) / 2048, 256, 0, stream>>>(dwn, dwnb, (long)NEXP_ * H_ * INTER_);
    cvt_k<<<(H_ * INTER_) / 2048, 256, 0, stream>>>(sdw, dwnb + (long)NEXP_ * H_ * INTER_, (long)H_ * INTER_);

    // ---- all 9 experts down -> bf16 partials, then weighted gather into out ----
    gemm2<2><<<dim3(T_ / 128, H_ / 128, NE9_), 256, 0, stream>>>(
        actm, dwnb, nullptr, pd, nullptr, cnt, offb,
        T_, H_, INTER_, INTER_, (long)H_ * INTER_);
    gather_k<<<T_, 256, 0, stream>>>(pd, offb, tep, tww, out);
}

// Round 15
// 481.019 us; speedup vs baseline: 1.1255x; 1.0179x over previous
//
#include <hip/hip_runtime.h>

typedef float f4 __attribute__((ext_vector_type(4)));
typedef float f32x4 __attribute__((ext_vector_type(4)));
typedef unsigned short us8 __attribute__((ext_vector_type(8)));
typedef __bf16 bf8 __attribute__((ext_vector_type(8)));

static constexpr int B_ = 2, S_ = 1024, H_ = 2048, T_ = B_ * S_;
static constexpr int NH_ = 16, DN_ = 128, DR_ = 64, DV_ = 128, DQK_ = 192;
static constexpr int KVL_ = 512, QL_ = 1536, INTER_ = 768, NEXP_ = 8, NE9_ = 9;
static constexpr int QKA_ = 2176;  // 1536 (q_a) + 576 (kv_a) + 64 pad
static constexpr float SCALING_ = 0.07216878364870322f; // 192^-0.5
static constexpr float EPS_ = 1e-6f;

__device__ __forceinline__ unsigned short f2bf(float f) {
    unsigned u = __float_as_uint(f);
    u += 0x7fffu + ((u >> 16) & 1u);
    return (unsigned short)(u >> 16);
}
__device__ __forceinline__ float bf2f(unsigned short h) {
    return __uint_as_float(((unsigned)h) << 16);
}
__device__ __forceinline__ us8 pack8(f4 a, f4 b) {
    us8 r;
    r[0] = f2bf(a[0]); r[1] = f2bf(a[1]); r[2] = f2bf(a[2]); r[3] = f2bf(a[3]);
    r[4] = f2bf(b[0]); r[5] = f2bf(b[1]); r[6] = f2bf(b[2]); r[7] = f2bf(b[3]);
    return r;
}

// async 16B/lane global->LDS. LDS dest = wave-uniform base + lane*16 (HW).
__device__ __forceinline__ void gload16(const unsigned short* g, unsigned short* lds) {
    __builtin_amdgcn_global_load_lds(
        (const __attribute__((address_space(1))) void*)g,
        (__attribute__((address_space(3))) void*)lds, 16, 0, 0);
}

// ---------------------------------------------------------------------------
// gemm2: C[M,N] = A[M,K] * B[N,K]^T, bf16 in, 128x128 tile, BK=64.
// 2-buffer counted pipeline: stage(t+1) -> vmcnt(8) -> bar -> compute(t) -> bar.
// Chunk-XOR swizzled LDS via pre-swizzled global source (r9-verified, 0 confl).
// MODE 0: plain. Cb -> bf16; else Cf (+add, may alias Cf) fp32.
// MODE 2: A rows compacted at off[e] (z=expert), C bf16 compacted rows.
// ---------------------------------------------------------------------------
template <int MODE>
__global__ __launch_bounds__(256) void gemm2(
    const unsigned short* __restrict__ A, const unsigned short* __restrict__ Bw,
    float* __restrict__ Cf, unsigned short* __restrict__ Cb,
    const float* __restrict__ add,
    const int* __restrict__ cnt, const int* __restrict__ off,
    int M, int N, int K, int ldA, long sB)
{
    constexpr int BM = 128, BN = 128, BK = 64;
    __shared__ __align__(16) unsigned short As[2][BM * BK];
    __shared__ __align__(16) unsigned short Bs[2][BN * BK];
    const int tid = threadIdx.x, lane = tid & 63, wv = tid >> 6;
    const int wm = (wv >> 1) * 64, wn = (wv & 1) * 64;

    const int nb = gridDim.x * gridDim.y;
    const int lin = blockIdx.y * gridDim.x + blockIdx.x;
    const int swz = (lin & 7) * (nb >> 3) + (lin >> 3);
    const int bx = swz % gridDim.x;
    const int by = swz / gridDim.x;
    const int m0 = bx * BM, n0 = by * BN;

    int mcnt = M, obase = 0;
    if constexpr (MODE == 2) {
        mcnt = cnt[blockIdx.z];
        if (m0 >= mcnt) return;
        obase = off[blockIdx.z];
    }

    const int srow = tid >> 3;                       // 0..31 within site
    const int scol = (((tid & 7) ^ (srow & 7)) * 8); // pre-swizzled global col
    long aoff[4], boff[4];
#pragma unroll
    for (int s = 0; s < 4; s++) {
        int r = m0 + s * 32 + srow;
        if constexpr (MODE == 2) {
            aoff[s] = (long)(obase + r) * ldA + scol;
        } else {
            aoff[s] = (long)r * ldA + scol;
        }
        boff[s] = (long)blockIdx.z * sB + (long)(n0 + s * 32 + srow) * K + scol;
    }

    f32x4 acc[4][4];
#pragma unroll
    for (int m = 0; m < 4; m++)
#pragma unroll
        for (int n = 0; n < 4; n++) acc[m][n] = f32x4{0.f, 0.f, 0.f, 0.f};

    const int fr = lane & 15, lg = lane >> 4;
    const int xr = fr & 7;

    auto stage = [&](int buf, int k0) {
#pragma unroll
        for (int s = 0; s < 4; s++)
            gload16(A + aoff[s] + k0, &As[buf][s * 2048 + wv * 512]);
#pragma unroll
        for (int s = 0; s < 4; s++)
            gload16(Bw + boff[s] + k0, &Bs[buf][s * 2048 + wv * 512]);
    };
    auto compute = [&](int buf) {
        __builtin_amdgcn_s_setprio(1);
        bf8 af[4][2], bfv[4][2];
#pragma unroll
        for (int m = 0; m < 4; m++) {
            int R = wm + m * 16 + fr;
#pragma unroll
            for (int ks = 0; ks < 2; ks++)
                af[m][ks] = *(const bf8*)&As[buf][R * 64 + ((ks * 4 + lg) ^ xr) * 8];
        }
#pragma unroll
        for (int n = 0; n < 4; n++) {
            int R = wn + n * 16 + fr;
#pragma unroll
            for (int ks = 0; ks < 2; ks++)
                bfv[n][ks] = *(const bf8*)&Bs[buf][R * 64 + ((ks * 4 + lg) ^ xr) * 8];
        }
#pragma unroll
        for (int m = 0; m < 4; m++)
#pragma unroll
            for (int n = 0; n < 4; n++) {
                acc[m][n] = __builtin_amdgcn_mfma_f32_16x16x32_bf16(af[m][0], bfv[n][0], acc[m][n], 0, 0, 0);
                acc[m][n] = __builtin_amdgcn_mfma_f32_16x16x32_bf16(af[m][1], bfv[n][1], acc[m][n], 0, 0, 0);
            }
        __builtin_amdgcn_s_setprio(0);
    };

    const int nt = K / BK;
    stage(0, 0);
    for (int t = 0; t < nt; t++) {
        if (t + 1 < nt) {
            stage((t & 1) ^ 1, (t + 1) * BK);
            asm volatile("s_waitcnt vmcnt(8)" ::: "memory");
        } else {
            asm volatile("s_waitcnt vmcnt(0)" ::: "memory");
        }
        __builtin_amdgcn_s_barrier();
        compute(t & 1);
        __builtin_amdgcn_s_barrier();
    }

#pragma unroll
    for (int m = 0; m < 4; m++) {
#pragma unroll
        for (int n = 0; n < 4; n++) {
#pragma unroll
            for (int i = 0; i < 4; i++) {
                int row = wm + m * 16 + lg * 4 + i;
                int col = n0 + wn + n * 16 + fr;
                float v = acc[m][n][i];
                if constexpr (MODE == 0) {
                    long idx = (long)(m0 + row) * N + col;
                    if (Cb)       Cb[idx] = f2bf(v);
                    else if (add) Cf[idx] = v + add[idx];
                    else          Cf[idx] = v;
                } else {
                    if (m0 + row < mcnt)
                        Cb[(long)(obase + m0 + row) * N + col] = f2bf(v);
                }
            }
        }
    }
}

// ---------------------------------------------------------------------------
// gemm_gu: fused MoE gate+up+silu, BM=64, BN=64 (+64 up). LDS 48 KB ->
// 3 blocks/CU (12 waves). Rows gathered via idxl[z]; epilogue writes
// actm = bf16(silu(g)*u) compacted at off[z]. 6 loads/thread -> vmcnt(6).
// ---------------------------------------------------------------------------
__global__ __launch_bounds__(256) void gemm_gu(
    const unsigned short* __restrict__ A, const unsigned short* __restrict__ Bw,
    unsigned short* __restrict__ actm,
    const int* __restrict__ cnt, const int* __restrict__ off,
    const int* __restrict__ idxl)
{
    constexpr int BM = 64, BN = 64, BK = 64, K = H_;
    __shared__ __align__(16) unsigned short As[2][BM * BK];   // 8 KB x2
    __shared__ __align__(16) unsigned short Bg[2][BN * BK];   // 8 KB x2
    __shared__ __align__(16) unsigned short Bu[2][BN * BK];   // 8 KB x2
    const int tid = threadIdx.x, lane = tid & 63, wv = tid >> 6;
    const int wm = (wv >> 1) * 32, wn = (wv & 1) * 32;

    const int nb = gridDim.x * gridDim.y;     // 32*12=384, %8==0
    const int lin = blockIdx.y * gridDim.x + blockIdx.x;
    const int swz = (lin & 7) * (nb >> 3) + (lin >> 3);
    const int bx = swz % gridDim.x;
    const int by = swz / gridDim.x;
    const int m0 = bx * BM, n0 = by * BN;
    const int e = blockIdx.z;

    const int mcnt = cnt[e];
    if (m0 >= mcnt) return;
    const int obase = off[e];

    const int srow = tid >> 3;
    const int scol = (((tid & 7) ^ (srow & 7)) * 8);
    long aoff[2], bgo[2], buo[2];
#pragma unroll
    for (int s = 0; s < 2; s++) {
        int r = m0 + s * 32 + srow;
        int rc = (r < mcnt) ? r : mcnt - 1;
        aoff[s] = (long)idxl[(long)e * T_ + rc] * H_ + scol;
        bgo[s] = ((long)e * (2 * INTER_) + n0 + s * 32 + srow) * K + scol;
        buo[s] = ((long)e * (2 * INTER_) + INTER_ + n0 + s * 32 + srow) * K + scol;
    }

    f32x4 ag[2][2], au[2][2];
#pragma unroll
    for (int m = 0; m < 2; m++)
#pragma unroll
        for (int n = 0; n < 2; n++) {
            ag[m][n] = f32x4{0.f, 0.f, 0.f, 0.f};
            au[m][n] = f32x4{0.f, 0.f, 0.f, 0.f};
        }

    const int fr = lane & 15, lg = lane >> 4;
    const int xr = fr & 7;

    auto stage = [&](int buf, int k0) {
#pragma unroll
        for (int s = 0; s < 2; s++)
            gload16(A + aoff[s] + k0, &As[buf][s * 2048 + wv * 512]);
#pragma unroll
        for (int s = 0; s < 2; s++)
            gload16(Bw + bgo[s] + k0, &Bg[buf][s * 2048 + wv * 512]);
#pragma unroll
        for (int s = 0; s < 2; s++)
            gload16(Bw + buo[s] + k0, &Bu[buf][s * 2048 + wv * 512]);
    };
    auto compute = [&](int buf) {
        __builtin_amdgcn_s_setprio(1);
        bf8 af[2][2], bgf[2][2], buf_[2][2];
#pragma unroll
        for (int m = 0; m < 2; m++) {
            int R = wm + m * 16 + fr;
#pragma unroll
            for (int ks = 0; ks < 2; ks++)
                af[m][ks] = *(const bf8*)&As[buf][R * 64 + ((ks * 4 + lg) ^ xr) * 8];
        }
#pragma unroll
        for (int n = 0; n < 2; n++) {
            int R = wn + n * 16 + fr;
#pragma unroll
            for (int ks = 0; ks < 2; ks++) {
                bgf[n][ks] = *(const bf8*)&Bg[buf][R * 64 + ((ks * 4 + lg) ^ xr) * 8];
                buf_[n][ks] = *(const bf8*)&Bu[buf][R * 64 + ((ks * 4 + lg) ^ xr) * 8];
            }
        }
#pragma unroll
        for (int m = 0; m < 2; m++)
#pragma unroll
            for (int n = 0; n < 2; n++) {
                ag[m][n] = __builtin_amdgcn_mfma_f32_16x16x32_bf16(af[m][0], bgf[n][0], ag[m][n], 0, 0, 0);
                ag[m][n] = __builtin_amdgcn_mfma_f32_16x16x32_bf16(af[m][1], bgf[n][1], ag[m][n], 0, 0, 0);
                au[m][n] = __builtin_amdgcn_mfma_f32_16x16x32_bf16(af[m][0], buf_[n][0], au[m][n], 0, 0, 0);
                au[m][n] = __builtin_amdgcn_mfma_f32_16x16x32_bf16(af[m][1], buf_[n][1], au[m][n], 0, 0, 0);
            }
        __builtin_amdgcn_s_setprio(0);
    };

    const int nt = K / BK;   // 32
    stage(0, 0);
    for (int t = 0; t < nt; t++) {
        if (t + 1 < nt) {
            stage((t & 1) ^ 1, (t + 1) * BK);
            asm volatile("s_waitcnt vmcnt(6)" ::: "memory");
        } else {
            asm volatile("s_waitcnt vmcnt(0)" ::: "memory");
        }
        __builtin_amdgcn_s_barrier();
        compute(t & 1);
        __builtin_amdgcn_s_barrier();
    }

#pragma unroll
    for (int m = 0; m < 2; m++) {
#pragma unroll
        for (int n = 0; n < 2; n++) {
#pragma unroll
            for (int i = 0; i < 4; i++) {
                int row = wm + m * 16 + lg * 4 + i;
                if (m0 + row < mcnt) {
                    float g = ag[m][n][i], u = au[m][n][i];
                    float v = g / (1.f + __expf(-g)) * u;
                    actm[(long)(obase + m0 + row) * INTER_ + n0 + wn + n * 16 + fr] = f2bf(v);
                }
            }
        }
    }
}

// ---------------------------------------------------------------------------
// Flash attention (causal). grid (S/64, B*NH), 256 threads (4 waves).
// q-tile index reversed for heads y>=16 so co-resident block pairs have
// complementary causal workloads (x, 15-x) -> balanced CUs.
// ---------------------------------------------------------------------------
__global__ __launch_bounds__(256) void fa_k(
    const unsigned short* __restrict__ qs, const unsigned short* __restrict__ ks,
    const unsigned short* __restrict__ vt, unsigned short* __restrict__ ab)
{
    constexpr int KB = 64;
    const int qx = (blockIdx.y & 16) ? (gridDim.x - 1 - (int)blockIdx.x) : (int)blockIdx.x;
    const int q0 = qx * 64;
    const int bh = blockIdx.y;
    const int b = bh >> 4, h = bh & 15;
    const int tid = threadIdx.x, lane = tid & 63, wv = tid >> 6;
    const int fr = lane & 15, lg = lane >> 4;
    const int ko = lg * 8;

    __shared__ __align__(16) unsigned short Kl[KB][200];
    __shared__ __align__(16) unsigned short Vl[128][72];
    __shared__ __align__(16) unsigned short Pl[4][16][72];

    const unsigned short* qp = qs + ((long)bh * S_ + q0 + wv * 16 + fr) * DQK_ + ko;
    bf8 qf[6];
#pragma unroll
    for (int s = 0; s < 6; s++) qf[s] = *(const bf8*)(qp + s * 32);

    f32x4 o[8];
#pragma unroll
    for (int n = 0; n < 8; n++) o[n] = f32x4{0.f, 0.f, 0.f, 0.f};
    float mrow[4] = {-3e38f, -3e38f, -3e38f, -3e38f};
    float lrow[4] = {0.f, 0.f, 0.f, 0.f};

    const int nt = q0 / KB + 1;

    const unsigned short* kg = ks + ((long)bh * S_ + (tid >> 2)) * DQK_ + (tid & 3) * 48;
    const unsigned short* vg = vt + ((long)bh * DV_ + (tid >> 1)) * S_ + (tid & 1) * 32;

    us8 krg[6], vrg[4];
#pragma unroll
    for (int j = 0; j < 6; j++) krg[j] = *(const us8*)(kg + j * 8);
#pragma unroll
    for (int j = 0; j < 4; j++) vrg[j] = *(const us8*)(vg + j * 8);

    for (int t = 0; t < nt; t++) {
        __syncthreads();
        {
            int r = tid >> 2, c = (tid & 3) * 48;
#pragma unroll
            for (int j = 0; j < 6; j++) *(us8*)&Kl[r][c + j * 8] = krg[j];
            int dv = tid >> 1, c2 = (tid & 1) * 32;
#pragma unroll
            for (int j = 0; j < 4; j++) *(us8*)&Vl[dv][c2 + j * 8] = vrg[j];
        }
        __syncthreads();
        if (t + 1 < nt) {
            long kof = (long)(t + 1) * KB;
#pragma unroll
            for (int j = 0; j < 6; j++) krg[j] = *(const us8*)(kg + kof * DQK_ + j * 8);
#pragma unroll
            for (int j = 0; j < 4; j++) vrg[j] = *(const us8*)(vg + kof + j * 8);
        }
        f32x4 ps[4];
#pragma unroll
        for (int ct = 0; ct < 4; ct++) {
            f32x4 a = f32x4{0.f, 0.f, 0.f, 0.f};
#pragma unroll
            for (int s = 0; s < 6; s++) {
                bf8 kf = *(const bf8*)&Kl[ct * 16 + fr][s * 32 + ko];
                a = __builtin_amdgcn_mfma_f32_16x16x32_bf16(qf[s], kf, a, 0, 0, 0);
            }
            ps[ct] = a;
        }
        const int kv0 = t * KB;
        const bool diag = (kv0 == q0);
#pragma unroll
        for (int ct = 0; ct < 4; ct++)
#pragma unroll
            for (int i = 0; i < 4; i++) {
                float v = ps[ct][i] * SCALING_;
                if (diag && (kv0 + ct * 16 + fr) > (q0 + wv * 16 + lg * 4 + i)) v = -3e38f;
                ps[ct][i] = v;
            }
        float scl[4];
#pragma unroll
        for (int i = 0; i < 4; i++) {
            float v = fmaxf(fmaxf(ps[0][i], ps[1][i]), fmaxf(ps[2][i], ps[3][i]));
#pragma unroll
            for (int x = 8; x; x >>= 1) v = fmaxf(v, __shfl_xor(v, x, 16));
            float mn = fmaxf(mrow[i], v);
            scl[i] = __expf(mrow[i] - mn);
            mrow[i] = mn;
        }
        float tsum[4] = {0.f, 0.f, 0.f, 0.f};
#pragma unroll
        for (int ct = 0; ct < 4; ct++)
#pragma unroll
            for (int i = 0; i < 4; i++) {
                float e = __expf(ps[ct][i] - mrow[i]);
                tsum[i] += e;
                Pl[wv][lg * 4 + i][ct * 16 + fr] = f2bf(e);
            }
#pragma unroll
        for (int i = 0; i < 4; i++) {
            float v = tsum[i];
#pragma unroll
            for (int x = 8; x; x >>= 1) v += __shfl_xor(v, x, 16);
            lrow[i] = lrow[i] * scl[i] + v;
        }
#pragma unroll
        for (int n = 0; n < 8; n++)
#pragma unroll
            for (int i = 0; i < 4; i++) o[n][i] *= scl[i];
        bf8 pf[2];
#pragma unroll
        for (int ksl = 0; ksl < 2; ksl++)
            pf[ksl] = *(const bf8*)&Pl[wv][fr][ksl * 32 + ko];
#pragma unroll
        for (int n = 0; n < 8; n++)
#pragma unroll
            for (int ksl = 0; ksl < 2; ksl++) {
                bf8 vf = *(const bf8*)&Vl[n * 16 + fr][ksl * 32 + ko];
                o[n] = __builtin_amdgcn_mfma_f32_16x16x32_bf16(pf[ksl], vf, o[n], 0, 0, 0);
            }
    }
#pragma unroll
    for (int i = 0; i < 4; i++) {
        float inv = 1.f / lrow[i];
        long rbase = ((long)b * S_ + q0 + wv * 16 + lg * 4 + i) * H_ + h * DV_;
#pragma unroll
        for (int n = 0; n < 8; n++)
            ab[rbase + n * 16 + fr] = f2bf(o[n][i] * inv);
    }
}

// ---------------------------------------------------------------------------
// conversion kernels (fp32 -> bf16), 8 elems/thread
// ---------------------------------------------------------------------------
__global__ __launch_bounds__(256) void cvt_k(
    const float* __restrict__ s, unsigned short* __restrict__ d, long n)
{
    long i = ((long)blockIdx.x * 256 + threadIdx.x) * 8;
    if (i < n) {
        f4 a = *(const f4*)(s + i);
        f4 b = *(const f4*)(s + i + 4);
        *(us8*)(d + i) = pack8(a, b);
    }
}

// merged q_a|kv_a weights: rows [0,1536)=qaw, [1536,2112)=kvaw, [2112,2176)=0
__global__ __launch_bounds__(256) void cvt_qka_k(
    const float* __restrict__ qa, const float* __restrict__ kva,
    unsigned short* __restrict__ d)
{
    long i = ((long)blockIdx.x * 256 + threadIdx.x) * 8;   // over 2176*2048
    long row = i >> 11, col = i & 2047;
    us8 o;
    if (row < QL_) {
        const float* s = qa + row * H_ + col;
        o = pack8(*(const f4*)s, *(const f4*)(s + 4));
    } else if (row < QL_ + 576) {
        const float* s = kva + (row - QL_) * H_ + col;
        o = pack8(*(const f4*)s, *(const f4*)(s + 4));
    } else {
        o = us8{0, 0, 0, 0, 0, 0, 0, 0};
    }
    *(us8*)(d + i) = o;
}

// 9-expert gate|up concat: z<8 routed (gw/uw), z==8 shared (sgw/suw)
__global__ __launch_bounds__(256) void cvt_cat9_k(
    const float* __restrict__ g, const float* __restrict__ u,
    const float* __restrict__ sg, const float* __restrict__ su,
    unsigned short* __restrict__ d)
{
    long ii = ((long)blockIdx.x * 256 + threadIdx.x) * 8;   // 1536*2048 per expert
    int e = blockIdx.y;
    long row = ii >> 11, col = ii & 2047;
    const float* src;
    if (row < INTER_)
        src = (e < 8) ? (g + ((long)e * INTER_ + row) * H_ + col) : (sg + row * H_ + col);
    else
        src = (e < 8) ? (u + ((long)e * INTER_ + row - INTER_) * H_ + col)
                      : (su + (row - INTER_) * H_ + col);
    *(us8*)(d + (long)e * (2 * INTER_) * H_ + ii) = pack8(*(const f4*)src, *(const f4*)(src + 4));
}

// ---------------------------------------------------------------------------
// rmsnorm fp32->bf16 (+ optional fp32 copy); cols == H_ == 2048 (8/thread)
__global__ __launch_bounds__(256) void rmsnorm_f2b(
    const float* __restrict__ in, const float* __restrict__ w,
    unsigned short* __restrict__ ob, float* __restrict__ of)
{
    const long base = (long)blockIdx.x * H_;
    const int c = threadIdx.x * 8;
    f4 v0 = *(const f4*)(in + base + c);
    f4 v1 = *(const f4*)(in + base + c + 4);
    float ss = v0[0] * v0[0] + v0[1] * v0[1] + v0[2] * v0[2] + v0[3] * v0[3]
             + v1[0] * v1[0] + v1[1] * v1[1] + v1[2] * v1[2] + v1[3] * v1[3];
#pragma unroll
    for (int o = 32; o; o >>= 1) ss += __shfl_down(ss, o);
    __shared__ float red[4];
    if ((threadIdx.x & 63) == 0) red[threadIdx.x >> 6] = ss;
    __syncthreads();
    float r = rsqrtf((red[0] + red[1] + red[2] + red[3]) / H_ + EPS_);
    f4 w0 = *(const f4*)(w + c);
    f4 w1 = *(const f4*)(w + c + 4);
    f4 a, b;
#pragma unroll
    for (int j = 0; j < 4; j++) { a[j] = v0[j] * r * w0[j]; b[j] = v1[j] * r * w1[j]; }
    *(us8*)(ob + base + c) = pack8(a, b);
    if (of) {
        *(f4*)(of + base + c) = a;
        *(f4*)(of + base + c + 4) = b;
    }
}

// bf16 in (istride) -> bf16 out (ostride); in==out safe (per-thread RBW)
__global__ __launch_bounds__(256) void rmsnorm_b2b(
    const unsigned short* __restrict__ in, const float* __restrict__ w,
    unsigned short* __restrict__ out, int cols, int istride, int ostride)
{
    const long ib = (long)blockIdx.x * istride;
    const long ob = (long)blockIdx.x * ostride;
    const int nu = cols >> 3;
    float ss = 0.f;
    for (int u = threadIdx.x; u < nu; u += 256) {
        us8 v = *(const us8*)(in + ib + u * 8);
#pragma unroll
        for (int j = 0; j < 8; j++) { float f = bf2f(v[j]); ss += f * f; }
    }
#pragma unroll
    for (int o = 32; o; o >>= 1) ss += __shfl_down(ss, o);
    __shared__ float red[4];
    if ((threadIdx.x & 63) == 0) red[threadIdx.x >> 6] = ss;
    __syncthreads();
    float r = rsqrtf((red[0] + red[1] + red[2] + red[3]) / cols + EPS_);
    for (int u = threadIdx.x; u < nu; u += 256) {
        us8 v = *(const us8*)(in + ib + u * 8);
        f4 w0 = *(const f4*)(w + u * 8);
        f4 w1 = *(const f4*)(w + u * 8 + 4);
        us8 o;
#pragma unroll
        for (int j = 0; j < 4; j++) o[j] = f2bf(bf2f(v[j]) * r * w0[j]);
#pragma unroll
        for (int j = 0; j < 4; j++) o[4 + j] = f2bf(bf2f(v[4 + j]) * r * w1[j]);
        *(us8*)(out + ob + u * 8) = o;
    }
}

// ---------------------------------------------------------------------------
// RoPE for q: 4 heads per 256-thread block (wave w = head)
__global__ __launch_bounds__(256) void rope_q_k(
    const unsigned short* __restrict__ q, const float* __restrict__ cs,
    const float* __restrict__ sn, unsigned short* __restrict__ qs)
{
    int t = blockIdx.x * 4 + (threadIdx.x >> 6);   // (b*S+s)*16 + h
    int h = t & 15;
    int bs = t >> 4;
    int s = bs & (S_ - 1);
    int b = bs >> 10;
    const unsigned short* qrow = q + (long)bs * (NH_ * DQK_) + h * DQK_;
    unsigned short* orow = qs + ((long)(b * NH_ + h) * S_ + s) * DQK_;
    int l = threadIdx.x & 63;
    orow[l] = qrow[l];
    orow[l + 64] = qrow[l + 64];
    int j = l & 31;
    float x0 = bf2f(qrow[DN_ + 2 * j]), x1 = bf2f(qrow[DN_ + 2 * j + 1]);
    float c = cs[(long)bs * DR_ + j], si = sn[(long)bs * DR_ + j];
    if (l < 32) orow[DN_ + j] = f2bf(x0 * c - x1 * si);
    else        orow[DN_ + 32 + j] = f2bf(x1 * c + x0 * si);
}

// k_rot lives in qkab cols [QL_+512, QL_+576), row stride QKA_
__global__ __launch_bounds__(64) void rope_k_k(
    const unsigned short* __restrict__ qkab, const float* __restrict__ cs,
    const float* __restrict__ sn, unsigned short* __restrict__ ks)
{
    int bs = blockIdx.x;
    int s = bs & (S_ - 1);
    int b = bs >> 10;
    const unsigned short* kr = qkab + (long)bs * QKA_ + QL_ + KVL_;
    int l = threadIdx.x;
    int j = l & 31;
    float x0 = bf2f(kr[2 * j]), x1 = bf2f(kr[2 * j + 1]);
    float c = cs[(long)bs * DR_ + j], si = sn[(long)bs * DR_ + j];
    float val = (l < 32) ? (x0 * c - x1 * si) : (x1 * c + x0 * si);
    int off = (l < 32) ? (DN_ + j) : (DN_ + 32 + j);
    unsigned short bv = f2bf(val);
    for (int h = 0; h < NH_; h++)
        ks[((long)(b * NH_ + h) * S_ + s) * DQK_ + off] = bv;
}

// kv split: kv (B,S,NH,256) -> ks[:, :128] rows + vt (B,NH,128,S) transpose.
// One pass over kv (replaces kpass_k + vt_k). grid (S/64, B*NH) x 256.
__global__ __launch_bounds__(256) void kvsplit_k(
    const unsigned short* __restrict__ kv, unsigned short* __restrict__ ks,
    unsigned short* __restrict__ vt)
{
    __shared__ unsigned short tile[64][264];
    int s0 = blockIdx.x * 64;
    int bh = blockIdx.y;
    int b = bh >> 4, h = bh & 15;
#pragma unroll
    for (int it = 0; it < 8; it++) {
        int idx = it * 256 + threadIdx.x;          // 2048 us8 units: 64 rows x 32
        int sl = idx >> 5, du = idx & 31;
        *(us8*)&tile[sl][du * 8] =
            *(const us8*)(kv + ((long)(b * S_ + s0 + sl) * NH_ + h) * 256 + du * 8);
    }
    __syncthreads();
    // k_pass: cols [0,128) -> ks rows (coalesced)
#pragma unroll
    for (int it = 0; it < 4; it++) {
        int idx = it * 256 + threadIdx.x;          // 1024 units: 64 rows x 16
        int sl = idx >> 4, du = idx & 15;
        *(us8*)(ks + ((long)bh * S_ + s0 + sl) * DQK_ + du * 8) = *(us8*)&tile[sl][du * 8];
    }
    // V^T: cols [128,256) -> vt[(bh*128+d)*S + s]
#pragma unroll
    for (int it = 0; it < 4; it++) {
        int idx = it * 256 + threadIdx.x;          // 1024 units: 128 d x 8 s-chunks
        int d = idx >> 3, su = idx & 7;
        us8 o;
#pragma unroll
        for (int j = 0; j < 8; j++) o[j] = tile[su * 8 + j][DN_ + d];
        *(us8*)(vt + ((long)bh * DV_ + d) * S_ + s0 + su * 8) = o;
    }
}

__global__ void zero9_k(int* __restrict__ cnt)
{
    if (threadIdx.x < NE9_) cnt[threadIdx.x] = (threadIdx.x == 8) ? T_ : 0;
}

__global__ void offs_k(const int* __restrict__ cnt, int* __restrict__ off)
{
    if (threadIdx.x == 0) {
        int a = 0;
        for (int e = 0; e < NE9_; e++) { off[e] = a; a += cnt[e]; }
    }
}

// router: top-2-of-grouped-8 scatter lists + per-token (e,p,w) records
// + identity entry for shared expert (e=8)
__global__ __launch_bounds__(64) void router_k(
    const float* __restrict__ h, const float* __restrict__ rw,
    const float* __restrict__ rb, int* __restrict__ cnt,
    int* __restrict__ idxl, int* __restrict__ tep, float* __restrict__ tww)
{
    int t = blockIdx.x;
    int l = threadIdx.x;
    const float* hr = h + (long)t * H_;
    float pe[8] = {0, 0, 0, 0, 0, 0, 0, 0};
    for (int k = l; k < H_; k += 64) {
        float hv = hr[k];
#pragma unroll
        for (int e = 0; e < 8; e++) pe[e] += hv * rw[e * H_ + k];
    }
#pragma unroll
    for (int e = 0; e < 8; e++)
        for (int o = 32; o; o >>= 1) pe[e] += __shfl_down(pe[e], o);
    if (l == 0) {
        float sr[8], sc[8];
#pragma unroll
        for (int e = 0; e < 8; e++) {
            sr[e] = 1.f / (1.f + __expf(-pe[e]));
            sc[e] = sr[e] + rb[e];
        }
        float gs[4];
        for (int g = 0; g < 4; g++) gs[g] = sc[2 * g] + sc[2 * g + 1];
        int g0 = 0;
        for (int g = 1; g < 4; g++) if (gs[g] > gs[g0]) g0 = g;
        int g1 = -1;
        for (int g = 0; g < 4; g++) {
            if (g == g0) continue;
            if (g1 < 0 || gs[g] > gs[g1]) g1 = g;
        }
        int i0 = -1, i1 = -1;
        for (int e = 0; e < 8; e++) {
            int g = e >> 1;
            if (g != g0 && g != g1) continue;
            if (i0 < 0 || sc[e] > sc[i0]) i0 = e;
        }
        for (int e = 0; e < 8; e++) {
            int g = e >> 1;
            if (g != g0 && g != g1) continue;
            if (e == i0) continue;
            if (i1 < 0 || sc[e] > sc[i1]) i1 = e;
        }
        float w0 = sr[i0], w1 = sr[i1];
        float inv = 2.5f / (w0 + w1 + 1e-20f);
        int p0 = atomicAdd(&cnt[i0], 1);
        idxl[i0 * T_ + p0] = t;
        int p1 = atomicAdd(&cnt[i1], 1);
        idxl[i1 * T_ + p1] = t;
        tep[t * 4 + 0] = i0; tep[t * 4 + 1] = p0;
        tep[t * 4 + 2] = i1; tep[t * 4 + 3] = p1;
        tww[t * 2 + 0] = w0 * inv;
        tww[t * 2 + 1] = w1 * inv;
        idxl[8 * T_ + t] = t;      // shared expert: identity list
    }
}

// out[t] += pd[shared_t] + w0*pd[pos0] + w1*pd[pos1]
__global__ __launch_bounds__(256) void gather_k(
    const unsigned short* __restrict__ pd, const int* __restrict__ off,
    const int* __restrict__ tep, const float* __restrict__ tww,
    float* __restrict__ out)
{
    int t = blockIdx.x;
    int e0 = tep[t * 4], p0 = tep[t * 4 + 1];
    int e1 = tep[t * 4 + 2], p1 = tep[t * 4 + 3];
    float w0 = tww[t * 2], w1 = tww[t * 2 + 1];
    long r0 = (long)(off[e0] + p0) * H_;
    long r1 = (long)(off[e1] + p1) * H_;
    long rs = (long)(off[8] + t) * H_;
    int c = threadIdx.x * 8;
    us8 a = *(const us8*)(pd + r0 + c);
    us8 b = *(const us8*)(pd + r1 + c);
    us8 s = *(const us8*)(pd + rs + c);
    float* op = out + (long)t * H_ + c;
#pragma unroll
    for (int j = 0; j < 8; j++)
        op[j] += bf2f(s[j]) + w0 * bf2f(a[j]) + w1 * bf2f(b[j]);
}

// ---------------------------------------------------------------------------
extern "C" void kernel_launch(void* const* d_in, const int* in_sizes, int n_in,
                              void* d_out, int out_size, void* d_ws, size_t ws_size,
                              hipStream_t stream)
{
    const float* hidden = (const float*)d_in[0];
    const float* cosb   = (const float*)d_in[1];
    const float* sinb   = (const float*)d_in[2];
    const float* ln1w   = (const float*)d_in[3];
    const float* qaw    = (const float*)d_in[4];
    const float* qalnw  = (const float*)d_in[5];
    const float* qbw    = (const float*)d_in[6];
    const float* kvaw   = (const float*)d_in[7];
    const float* kvalnw = (const float*)d_in[8];
    const float* kvbw   = (const float*)d_in[9];
    const float* ow     = (const float*)d_in[10];
    const float* ln2w   = (const float*)d_in[11];
    const float* rw     = (const float*)d_in[12];
    const float* rb     = (const float*)d_in[13];
    const float* gw     = (const float*)d_in[14];
    const float* uw     = (const float*)d_in[15];
    const float* dwn    = (const float*)d_in[16];
    const float* sgw    = (const float*)d_in[17];
    const float* suw    = (const float*)d_in[18];
    const float* sdw    = (const float*)d_in[19];
    float* out = (float*)d_out;
    (void)in_sizes; (void)n_in; (void)out_size; (void)ws_size;

    char* ws = (char*)d_ws;
    const size_t MB = 1u << 20;
    // ---- phase A (attention), MiB offsets ----
    unsigned short* qkawb = (unsigned short*)(ws + 0 * MB);   // 8.5 (2176x2048)
    unsigned short* qbwb  = (unsigned short*)(ws + 9 * MB);   // 9
    unsigned short* kvbwb = (unsigned short*)(ws + 18 * MB);  // 4
    unsigned short* owb   = (unsigned short*)(ws + 22 * MB);  // 8
    unsigned short* xb    = (unsigned short*)(ws + 30 * MB);  // 8
    unsigned short* qkab  = (unsigned short*)(ws + 38 * MB);  // 8.5 (T x 2176)
    unsigned short* qb16  = (unsigned short*)(ws + 47 * MB);  // 12
    unsigned short* ckvnb = (unsigned short*)(ws + 59 * MB);  // 2
    unsigned short* kvb   = (unsigned short*)(ws + 61 * MB);  // 16
    unsigned short* qs    = (unsigned short*)(ws + 77 * MB);  // 12
    unsigned short* ks    = (unsigned short*)(ws + 89 * MB);  // 12
    unsigned short* vt    = (unsigned short*)(ws + 30 * MB);  // 8  (alias xb)
    unsigned short* ab    = (unsigned short*)(ws + 38 * MB);  // 8  (alias qkab, dead by FA)
    // ---- phase B (MoE) ----
    float* hbuf = (float*)(ws + 0 * MB);                      // 16 (dead after router)
    unsigned short* actm = (unsigned short*)(ws + 0 * MB);    // 9.4 (6144x768, after router)
    unsigned short* hb16 = (unsigned short*)(ws + 16 * MB);   // 8
    int*   cnt  = (int*)(ws + 24 * MB);
    int*   offb = (int*)(ws + 24 * MB + 256);
    int*   idxl = (int*)(ws + 24 * MB + 512);                 // 72 KB (9 x T)
    int*   tep  = (int*)(ws + 24 * MB + 512 + 9 * T_ * 4);    // 32 KB
    float* tww  = (float*)(ws + 24 * MB + 512 + 9 * T_ * 4 + 4 * T_ * 4); // 16 KB
    unsigned short* guwb = (unsigned short*)(ws + 25 * MB);   // 54 (9x1536x2048)
    unsigned short* dwnb = (unsigned short*)(ws + 25 * MB);   // 27 (alias guwb, after gu)
    unsigned short* pd   = (unsigned short*)(ws + 79 * MB);   // 24 (6144x2048 bf16)

    // ---- weight conversion (attention) ----
    cvt_qka_k<<<(QKA_ * H_) / 2048, 256, 0, stream>>>(qaw, kvaw, qkawb);
    cvt_k<<<(NH_ * DQK_ * QL_) / 2048, 256, 0, stream>>>(qbw, qbwb, (long)NH_ * DQK_ * QL_);
    cvt_k<<<(NH_ * 256 * KVL_) / 2048, 256, 0, stream>>>(kvbw, kvbwb, (long)NH_ * 256 * KVL_);
    cvt_k<<<(H_ * H_) / 2048, 256, 0, stream>>>(ow, owb, (long)H_ * H_);

    // ---- attention projections ----
    rmsnorm_f2b<<<T_, 256, 0, stream>>>(hidden, ln1w, xb, nullptr);

    gemm2<0><<<dim3(T_ / 128, QKA_ / 128, 1), 256, 0, stream>>>(
        xb, qkawb, nullptr, qkab, nullptr, nullptr, nullptr,
        T_, QKA_, H_, H_, 0);
    rmsnorm_b2b<<<T_, 256, 0, stream>>>(qkab, qalnw, qkab, QL_, QKA_, QKA_);
    gemm2<0><<<dim3(T_ / 128, (NH_ * DQK_) / 128, 1), 256, 0, stream>>>(
        qkab, qbwb, nullptr, qb16, nullptr, nullptr, nullptr,
        T_, NH_ * DQK_, QL_, QKA_, 0);
    rmsnorm_b2b<<<T_, 256, 0, stream>>>(qkab + QL_, kvalnw, ckvnb, KVL_, QKA_, KVL_);
    gemm2<0><<<dim3(T_ / 128, (NH_ * 256) / 128, 1), 256, 0, stream>>>(
        ckvnb, kvbwb, nullptr, kvb, nullptr, nullptr, nullptr,
        T_, NH_ * 256, KVL_, KVL_, 0);

    // ---- assemble qs / ks / vt ----
    rope_q_k<<<(T_ * NH_) / 4, 256, 0, stream>>>(qb16, cosb, sinb, qs);
    rope_k_k<<<T_, 64, 0, stream>>>(qkab, cosb, sinb, ks);
    kvsplit_k<<<dim3(S_ / 64, B_ * NH_), 256, 0, stream>>>(kvb, ks, vt);

    // ---- flash attention (causal-balanced) ----
    fa_k<<<dim3(S_ / 64, B_ * NH_), 256, 0, stream>>>(qs, ks, vt, ab);

    // ---- o-proj + residual: out = attn @ ow^T + hidden ----
    gemm2<0><<<dim3(T_ / 128, H_ / 128, 1), 256, 0, stream>>>(
        ab, owb, out, nullptr, hidden, nullptr, nullptr,
        T_, H_, H_, H_, 0);

    // ---- MoE prep ----
    rmsnorm_f2b<<<T_, 256, 0, stream>>>(out, ln2w, hb16, hbuf);
    zero9_k<<<1, 64, 0, stream>>>(cnt);
    router_k<<<T_, 64, 0, stream>>>(hbuf, rw, rb, cnt, idxl, tep, tww);
    offs_k<<<1, 64, 0, stream>>>(cnt, offb);

    // ---- 9-expert fused gate+up+silu -> actm (compacted bf16) ----
    cvt_cat9_k<<<dim3((2 * INTER_ * H_) / 2048, NE9_), 256, 0, stream>>>(gw, uw, sgw, suw, guwb);
    gemm_gu<<<dim3(T_ / 64, INTER_ / 64, NE9_), 256, 0, stream>>>(
        hb16, guwb, actm, cnt, offb, idxl);

    // ---- down weights (routed 0..7 then shared at index 8) ----
    cvt_k<<<(NEXP_ * H_ * INTER_) / 2048, 256, 0, stream>>>(dwn, dwnb, (long)NEXP_ * H_ * INTER_);
    cvt_k<<<(H_ * INTER_) / 2048, 256, 0, stream>>>(sdw, dwnb + (long)NEXP_ * H_ * INTER_, (long)H_ * INTER_);

    // ---- all 9 experts down -> bf16 partials, then weighted gather into out ----
    gemm2<2><<<dim3(T_ / 128, H_ / 128, NE9_), 256, 0, stream>>>(
        actm, dwnb, nullptr, pd, nullptr, cnt, offb,
        T_, H_, INTER_, INTER_, (long)H_ * INTER_);
    gather_k<<<T_, 256, 0, stream>>>(pd, offb, tep, tww, out);
}